// Round 1
// baseline (2335.810 us; speedup 1.0000x reference)
//
#include <hip/hip_runtime.h>
#include <hip/hip_bf16.h>

// Problem constants (match reference)
#define NN   100000      // NU == NI
#define ER_  500000
#define EA_  500000
#define BM 128
#define BN 128
#define BK 32

// ---------------------------------------------------------------------------
// CSR build
// ---------------------------------------------------------------------------
__global__ void count_deg(const int* __restrict__ dst, int n_edges, int* __restrict__ cnt) {
    int i = blockIdx.x * blockDim.x + threadIdx.x;
    if (i < n_edges) atomicAdd(&cnt[dst[i]], 1);
}

__global__ void fill_csr(const int* __restrict__ dst, const int* __restrict__ src, int n_edges,
                         const int* __restrict__ ptr, int* __restrict__ cur, int* __restrict__ col) {
    int i = blockIdx.x * blockDim.x + threadIdx.x;
    if (i < n_edges) {
        int d = dst[i];
        int slot = ptr[d] + atomicAdd(&cur[d], 1);
        col[slot] = src[i];
    }
}

// 3 independent exclusive scans, one block each (n = NN for all three).
__global__ void exscan3(const int* __restrict__ c0, int* __restrict__ p0,
                        const int* __restrict__ c1, int* __restrict__ p1,
                        const int* __restrict__ c2, int* __restrict__ p2, int n) {
    const int* cnt = (blockIdx.x == 0) ? c0 : (blockIdx.x == 1) ? c1 : c2;
    int*       ptr = (blockIdx.x == 0) ? p0 : (blockIdx.x == 1) ? p1 : p2;
    __shared__ int wsum[16];
    __shared__ int s_carry, s_tot;
    int tid = threadIdx.x, lane = tid & 63, wid = tid >> 6;
    if (tid == 0) s_carry = 0;
    __syncthreads();
    for (int base = 0; base < n; base += 4096) {
        int i0 = base + tid * 4;
        int4 v = {0, 0, 0, 0};
        if (i0 + 3 < n) v = *(const int4*)(cnt + i0);
        else {
            if (i0     < n) v.x = cnt[i0];
            if (i0 + 1 < n) v.y = cnt[i0 + 1];
            if (i0 + 2 < n) v.z = cnt[i0 + 2];
        }
        int s = v.x + v.y + v.z + v.w;
        int isc = s;
        #pragma unroll
        for (int off = 1; off < 64; off <<= 1) {
            int t = __shfl_up(isc, off, 64);
            if (lane >= off) isc += t;
        }
        if (lane == 63) wsum[wid] = isc;
        __syncthreads();
        if (wid == 0) {
            int w = (lane < 16) ? wsum[lane] : 0;
            int wsc = w;
            #pragma unroll
            for (int off = 1; off < 16; off <<= 1) {
                int t = __shfl_up(wsc, off, 64);
                if (lane >= off) wsc += t;
            }
            if (lane < 16) wsum[lane] = wsc - w;   // exclusive wave offsets
            if (lane == 15) s_tot = wsc;           // chunk total
        }
        __syncthreads();
        int excl = s_carry + wsum[wid] + (isc - s);
        if (i0     < n) ptr[i0]     = excl;
        if (i0 + 1 < n) ptr[i0 + 1] = excl + v.x;
        if (i0 + 2 < n) ptr[i0 + 2] = excl + v.x + v.y;
        if (i0 + 3 < n) ptr[i0 + 3] = excl + v.x + v.y + v.z;
        __syncthreads();
        if (tid == 0) s_carry += s_tot;
        __syncthreads();
    }
    if (tid == 0) ptr[n] = s_carry;
}

// ---------------------------------------------------------------------------
// Aggregation: mean of gathered rows per CSR node. Empty set -> 0.
// ---------------------------------------------------------------------------
// D=128: half-wave (32 lanes) per node, float4/lane.
__global__ void agg_mean128(const float* __restrict__ x, const int* __restrict__ ptr,
                            const int* __restrict__ col, float* __restrict__ out, int n) {
    int g = blockIdx.x * blockDim.x + threadIdx.x;
    int node = g >> 5, l = g & 31;
    if (node >= n) return;
    int p0 = ptr[node], p1 = ptr[node + 1];
    float4 acc = {0.f, 0.f, 0.f, 0.f};
    int off = l * 4;
    for (int e = p0; e < p1; ++e) {
        int s = col[e];
        float4 v = *(const float4*)(x + (size_t)s * 128 + off);
        acc.x += v.x; acc.y += v.y; acc.z += v.z; acc.w += v.w;
    }
    float inv = (p1 > p0) ? 1.0f / (float)(p1 - p0) : 0.0f;
    *(float4*)(out + (size_t)node * 128 + off) =
        make_float4(acc.x * inv, acc.y * inv, acc.z * inv, acc.w * inv);
}

// D=256: full wave (64 lanes) per node, float4/lane.
__global__ void agg_mean256(const float* __restrict__ x, const int* __restrict__ ptr,
                            const int* __restrict__ col, float* __restrict__ out, int n) {
    int g = blockIdx.x * blockDim.x + threadIdx.x;
    int node = g >> 6, l = g & 63;
    if (node >= n) return;
    int p0 = ptr[node], p1 = ptr[node + 1];
    float4 acc = {0.f, 0.f, 0.f, 0.f};
    int off = l * 4;
    for (int e = p0; e < p1; ++e) {
        int s = col[e];
        float4 v = *(const float4*)(x + (size_t)s * 256 + off);
        acc.x += v.x; acc.y += v.y; acc.z += v.z; acc.w += v.w;
    }
    float inv = (p1 > p0) ? 1.0f / (float)(p1 - p0) : 0.0f;
    *(float4*)(out + (size_t)node * 256 + off) =
        make_float4(acc.x * inv, acc.y * inv, acc.z * inv, acc.w * inv);
}

// ---------------------------------------------------------------------------
// small elementwise add (weight combine)
// ---------------------------------------------------------------------------
__global__ void add2(const float* __restrict__ a, const float* __restrict__ b,
                     float* __restrict__ o, int n) {
    int i = blockIdx.x * blockDim.x + threadIdx.x;
    if (i < n) o[i] = a[i] + b[i];
}

// ---------------------------------------------------------------------------
// fp32 tiled GEMM, N fixed = 256, up to 2 (A,W,K) parts accumulated.
// C[M,256] (+)= sum_p A_p[M,K_p] @ W_p[K_p,256]  (+ bias0 + bias1) (relu)
// flags: bit0 = accumulate into existing C, bit1 = relu
// grid: (ceil(M/128), 2), block 256
// ---------------------------------------------------------------------------
__global__ __launch_bounds__(256)
void gemm2p(const float* __restrict__ A0, const float* __restrict__ W0, int K0,
            const float* __restrict__ A1, const float* __restrict__ W1, int K1,
            const float* __restrict__ b0, const float* __restrict__ b1,
            float* __restrict__ C, int M, int flags) {
    __shared__ float sA[BK][BM + 4];   // [k][m], +4 pad keeps 16B row alignment
    __shared__ float sW[BK][BN];       // [k][n]
    const int m0 = blockIdx.x * BM;
    const int n0 = blockIdx.y * BN;
    const int tid = threadIdx.x;
    const int tm = (tid >> 4) << 3;    // 0..120
    const int tn = (tid & 15) << 3;    // 0..120
    const int ac4 = (tid & 7) << 2;    // A-tile k offset 0..28
    const int ar  = tid >> 3;          // A-tile row 0..31
    const int wc  = (tid & 31) << 2;   // W-tile col 0..124
    const int wr  = tid >> 5;          // W-tile row 0..7

    float acc[8][8];
    #pragma unroll
    for (int i = 0; i < 8; i++)
        #pragma unroll
        for (int j = 0; j < 8; j++) acc[i][j] = 0.f;

    #pragma unroll 1
    for (int part = 0; part < 2; ++part) {
        const float* A = part ? A1 : A0;
        const float* W = part ? W1 : W0;
        const int    K = part ? K1 : K0;
        if (!A) break;
        #pragma unroll 1
        for (int k0 = 0; k0 < K; k0 += BK) {
            #pragma unroll
            for (int it = 0; it < 4; ++it) {
                int m = ar + it * 32;
                int gm = m0 + m;
                float4 v = make_float4(0.f, 0.f, 0.f, 0.f);
                if (gm < M) v = *(const float4*)(A + (size_t)gm * K + (k0 + ac4));
                sA[ac4 + 0][m] = v.x; sA[ac4 + 1][m] = v.y;
                sA[ac4 + 2][m] = v.z; sA[ac4 + 3][m] = v.w;
            }
            #pragma unroll
            for (int it = 0; it < 4; ++it) {
                int k = wr + it * 8;
                *(float4*)&sW[k][wc] = *(const float4*)(W + (size_t)(k0 + k) * 256 + (n0 + wc));
            }
            __syncthreads();
            #pragma unroll
            for (int kk = 0; kk < BK; ++kk) {
                float a[8], b[8];
                *(float4*)(a)     = *(const float4*)&sA[kk][tm];
                *(float4*)(a + 4) = *(const float4*)&sA[kk][tm + 4];
                *(float4*)(b)     = *(const float4*)&sW[kk][tn];
                *(float4*)(b + 4) = *(const float4*)&sW[kk][tn + 4];
                #pragma unroll
                for (int i = 0; i < 8; i++)
                    #pragma unroll
                    for (int j = 0; j < 8; j++)
                        acc[i][j] = fmaf(a[i], b[j], acc[i][j]);
            }
            __syncthreads();
        }
    }

    float bb[8];
    #pragma unroll
    for (int j = 0; j < 8; j++) {
        float v = 0.f;
        if (b0) v += b0[n0 + tn + j];
        if (b1) v += b1[n0 + tn + j];
        bb[j] = v;
    }
    const bool accum = flags & 1, relu = flags & 2;
    #pragma unroll
    for (int i = 0; i < 8; i++) {
        int gm = m0 + tm + i;
        if (gm < M) {
            float* dst = C + (size_t)gm * 256 + n0 + tn;
            float r[8];
            if (accum) {
                float4 o0 = *(float4*)dst, o1 = *(float4*)(dst + 4);
                r[0]=o0.x; r[1]=o0.y; r[2]=o0.z; r[3]=o0.w;
                r[4]=o1.x; r[5]=o1.y; r[6]=o1.z; r[7]=o1.w;
            } else {
                #pragma unroll
                for (int j = 0; j < 8; j++) r[j] = 0.f;
            }
            #pragma unroll
            for (int j = 0; j < 8; j++) {
                float v = r[j] + acc[i][j] + bb[j];
                if (relu) v = fmaxf(v, 0.f);
                r[j] = v;
            }
            *(float4*)dst       = make_float4(r[0], r[1], r[2], r[3]);
            *(float4*)(dst + 4) = make_float4(r[4], r[5], r[6], r[7]);
        }
    }
}

// ---------------------------------------------------------------------------
extern "C" void kernel_launch(void* const* d_in, const int* in_sizes, int n_in,
                              void* d_out, int out_size, void* d_ws, size_t ws_size,
                              hipStream_t stream) {
    const float* x_user = (const float*)d_in[0];
    const float* x_item = (const float*)d_in[1];
    const int* src_rev  = (const int*)d_in[2];
    const int* dst_rev  = (const int*)d_in[3];
    const int* src_ab   = (const int*)d_in[4];
    const int* dst_ab   = (const int*)d_in[5];
    const float* Wl1_rev  = (const float*)d_in[6];
    const float* Wr1_rev  = (const float*)d_in[7];
    const float* b1_rev   = (const float*)d_in[8];
    const float* Wl1_rrev = (const float*)d_in[9];
    const float* Wr1_rrev = (const float*)d_in[10];
    const float* b1_rrev  = (const float*)d_in[11];
    const float* Wl1_ab   = (const float*)d_in[12];
    const float* Wr1_ab   = (const float*)d_in[13];
    const float* b1_ab    = (const float*)d_in[14];
    const float* Wl2_rev  = (const float*)d_in[15];
    const float* Wr2_rev  = (const float*)d_in[16];
    const float* b2_rev   = (const float*)d_in[17];
    const float* Wl2_rrev = (const float*)d_in[18];
    const float* Wr2_rrev = (const float*)d_in[19];
    const float* b2_rrev  = (const float*)d_in[20];
    const float* Wl2_ab   = (const float*)d_in[21];
    const float* Wr2_ab   = (const float*)d_in[22];
    const float* b2_ab    = (const float*)d_in[23];

    float* o_user = (float*)d_out;                       // [NN,256]
    float* o_item = (float*)d_out + (size_t)NN * 256;    // [NN,256]

    // ---- workspace layout (~316 MB) ----
    char* ws = (char*)d_ws;
    size_t off = 0;
    auto alloc = [&](size_t bytes) -> void* {
        void* p = ws + off;
        off += (bytes + 255) & ~(size_t)255;
        return p;
    };
    float* slab   = (float*)alloc((size_t)NN * 256 * 4);  // reusable mean buffer (fits 128 & 256)
    float* h_item = (float*)alloc((size_t)NN * 256 * 4);
    float* h_user = (float*)alloc((size_t)NN * 256 * 4);
    float* Wr1c   = (float*)alloc(128 * 256 * 4);
    float* Wr2c   = (float*)alloc(256 * 256 * 4);
    int* ptrA = (int*)alloc((NN + 1) * 4);
    int* ptrB = (int*)alloc((NN + 1) * 4);
    int* ptrC = (int*)alloc((NN + 1) * 4);
    int* colA = (int*)alloc((size_t)ER_ * 4);
    int* colB = (int*)alloc((size_t)EA_ * 4);
    int* colC = (int*)alloc((size_t)ER_ * 4);
    int* curA = (int*)alloc((size_t)3 * NN * 4);  // A,B,C contiguous for one memset
    int* curB = curA + NN;
    int* curC = curA + 2 * NN;

    const int TPB = 256;
    dim3 egrid((ER_ + TPB - 1) / TPB);

    // ---- CSR build (topology shared by both layers) ----
    // A: reviews grouped by dst(item), col = src(user)
    // B: also_bought grouped by dst(item), col = src(item)
    // C: reviews grouped by src(user), col = dst(item)   [rev_reviews]
    hipMemsetAsync(curA, 0, (size_t)3 * NN * 4, stream);
    count_deg<<<egrid, TPB, 0, stream>>>(dst_rev, ER_, curA);
    count_deg<<<egrid, TPB, 0, stream>>>(dst_ab,  EA_, curB);
    count_deg<<<egrid, TPB, 0, stream>>>(src_rev, ER_, curC);
    exscan3<<<3, 1024, 0, stream>>>(curA, ptrA, curB, ptrB, curC, ptrC, NN);
    hipMemsetAsync(curA, 0, (size_t)3 * NN * 4, stream);
    fill_csr<<<egrid, TPB, 0, stream>>>(dst_rev, src_rev, ER_, ptrA, curA, colA);
    fill_csr<<<egrid, TPB, 0, stream>>>(dst_ab,  src_ab,  EA_, ptrB, curB, colB);
    fill_csr<<<egrid, TPB, 0, stream>>>(src_rev, dst_rev, ER_, ptrC, curC, colC);

    // ---- combined root weights ----
    add2<<<(128 * 256 + TPB - 1) / TPB, TPB, 0, stream>>>(Wr1_rev, Wr1_ab, Wr1c, 128 * 256);
    add2<<<(256 * 256 + TPB - 1) / TPB, TPB, 0, stream>>>(Wr2_rev, Wr2_ab, Wr2c, 256 * 256);

    dim3 ggrid((NN + BM - 1) / BM, 2);

    // ---- layer 1 ----
    // h_item = relu(mean_A(x_user)@Wl1_rev + mean_B(x_item)@Wl1_ab + x_item@(Wr1_rev+Wr1_ab) + b1_rev + b1_ab)
    agg_mean128<<<(NN * 32) / TPB, TPB, 0, stream>>>(x_user, ptrA, colA, slab, NN);
    gemm2p<<<ggrid, TPB, 0, stream>>>(slab, Wl1_rev, 128, x_item, Wr1c, 128,
                                      b1_rev, b1_ab, h_item, NN, /*init*/0);
    agg_mean128<<<(NN * 32) / TPB, TPB, 0, stream>>>(x_item, ptrB, colB, slab, NN);
    gemm2p<<<ggrid, TPB, 0, stream>>>(slab, Wl1_ab, 128, nullptr, nullptr, 0,
                                      nullptr, nullptr, h_item, NN, /*accum|relu*/3);
    // h_user = relu(mean_C(x_item)@Wl1_rrev + x_user@Wr1_rrev + b1_rrev)
    agg_mean128<<<(NN * 32) / TPB, TPB, 0, stream>>>(x_item, ptrC, colC, slab, NN);
    gemm2p<<<ggrid, TPB, 0, stream>>>(slab, Wl1_rrev, 128, x_user, Wr1_rrev, 128,
                                      b1_rrev, nullptr, h_user, NN, /*init|relu*/2);

    // ---- layer 2 ----
    // o_item = mean_A(h_user)@Wl2_rev + mean_B(h_item)@Wl2_ab + h_item@(Wr2_rev+Wr2_ab) + b2_rev + b2_ab
    agg_mean256<<<(NN * 64) / TPB, TPB, 0, stream>>>(h_user, ptrA, colA, slab, NN);
    gemm2p<<<ggrid, TPB, 0, stream>>>(slab, Wl2_rev, 256, h_item, Wr2c, 256,
                                      b2_rev, b2_ab, o_item, NN, 0);
    agg_mean256<<<(NN * 64) / TPB, TPB, 0, stream>>>(h_item, ptrB, colB, slab, NN);
    gemm2p<<<ggrid, TPB, 0, stream>>>(slab, Wl2_ab, 256, nullptr, nullptr, 0,
                                      nullptr, nullptr, o_item, NN, 1);
    // o_user = mean_C(h_item)@Wl2_rrev + h_user@Wr2_rrev + b2_rrev
    agg_mean256<<<(NN * 64) / TPB, TPB, 0, stream>>>(h_item, ptrC, colC, slab, NN);
    gemm2p<<<ggrid, TPB, 0, stream>>>(slab, Wl2_rrev, 256, h_user, Wr2_rrev, 256,
                                      b2_rrev, nullptr, o_user, NN, 0);
}

// Round 3
// 1696.600 us; speedup vs baseline: 1.3768x; 1.3768x over previous
//
#include <hip/hip_runtime.h>
#include <hip/hip_bf16.h>

#define NN    100000
#define MPAD  100096          // 1564 * 64, >= NN, padded rows zeroed/ignored
#define ER_   500000
#define EA_   500000

#define F_ACCF    1
#define F_RELU    2
#define F_PAIROUT 4
#define F_PAIRACC 8

typedef __attribute__((ext_vector_type(8))) short bf16x8;
typedef __attribute__((ext_vector_type(4))) float f32x4;

__device__ __forceinline__ ushort f2bf(float f) {
    union { __hip_bfloat16 h; ushort u; } c; c.h = __float2bfloat16(f); return c.u;
}
__device__ __forceinline__ float bf2f(ushort u) {
    union { ushort u; __hip_bfloat16 h; } c; c.u = u; return __bfloat162float(c.h);
}
__device__ __forceinline__ void split1(float v, ushort& h, ushort& l) {
    h = f2bf(v); l = f2bf(v - bf2f(h));
}

// ---------------------------------------------------------------------------
// CSR build
// ---------------------------------------------------------------------------
__global__ void count_deg(const int* __restrict__ dst, int n_edges, int* __restrict__ cnt) {
    int i = blockIdx.x * blockDim.x + threadIdx.x;
    if (i < n_edges) atomicAdd(&cnt[dst[i]], 1);
}

__global__ void fill_csr(const int* __restrict__ dst, const int* __restrict__ src, int n_edges,
                         const int* __restrict__ ptr, int* __restrict__ cur, int* __restrict__ col) {
    int i = blockIdx.x * blockDim.x + threadIdx.x;
    if (i < n_edges) {
        int d = dst[i];
        int slot = ptr[d] + atomicAdd(&cur[d], 1);
        col[slot] = src[i];
    }
}

__global__ void exscan3(const int* __restrict__ c0, int* __restrict__ p0,
                        const int* __restrict__ c1, int* __restrict__ p1,
                        const int* __restrict__ c2, int* __restrict__ p2, int n) {
    const int* cnt = (blockIdx.x == 0) ? c0 : (blockIdx.x == 1) ? c1 : c2;
    int*       ptr = (blockIdx.x == 0) ? p0 : (blockIdx.x == 1) ? p1 : p2;
    __shared__ int wsum[16];
    __shared__ int s_carry, s_tot;
    int tid = threadIdx.x, lane = tid & 63, wid = tid >> 6;
    if (tid == 0) s_carry = 0;
    __syncthreads();
    for (int base = 0; base < n; base += 4096) {
        int i0 = base + tid * 4;
        int4 v = {0, 0, 0, 0};
        if (i0 + 3 < n) v = *(const int4*)(cnt + i0);
        else {
            if (i0     < n) v.x = cnt[i0];
            if (i0 + 1 < n) v.y = cnt[i0 + 1];
            if (i0 + 2 < n) v.z = cnt[i0 + 2];
        }
        int s = v.x + v.y + v.z + v.w;
        int isc = s;
        #pragma unroll
        for (int off = 1; off < 64; off <<= 1) {
            int t = __shfl_up(isc, off, 64);
            if (lane >= off) isc += t;
        }
        if (lane == 63) wsum[wid] = isc;
        __syncthreads();
        if (wid == 0) {
            int w = (lane < 16) ? wsum[lane] : 0;
            int wsc = w;
            #pragma unroll
            for (int off = 1; off < 16; off <<= 1) {
                int t = __shfl_up(wsc, off, 64);
                if (lane >= off) wsc += t;
            }
            if (lane < 16) wsum[lane] = wsc - w;
            if (lane == 15) s_tot = wsc;
        }
        __syncthreads();
        int excl = s_carry + wsum[wid] + (isc - s);
        if (i0     < n) ptr[i0]     = excl;
        if (i0 + 1 < n) ptr[i0 + 1] = excl + v.x;
        if (i0 + 2 < n) ptr[i0 + 2] = excl + v.x + v.y;
        if (i0 + 3 < n) ptr[i0 + 3] = excl + v.x + v.y + v.z;
        __syncthreads();
        if (tid == 0) s_carry += s_tot;
        __syncthreads();
    }
    if (tid == 0) ptr[n] = s_carry;
}

// ---------------------------------------------------------------------------
// Weight prep: W[K][256] fp32 (+ optional addend) -> transposed hi/lo bf16
// planes Wt[n][k] ([256][K]).
// ---------------------------------------------------------------------------
__global__ void wprep(const float* __restrict__ W0, const float* __restrict__ W1, int K,
                      ushort* __restrict__ hiT, ushort* __restrict__ loT) {
    int i = blockIdx.x * blockDim.x + threadIdx.x;
    if (i >= K * 256) return;
    int k = i >> 8, n = i & 255;
    float v = W0[i];
    if (W1) v += W1[i];
    ushort h, l; split1(v, h, l);
    hiT[n * K + k] = h; loT[n * K + k] = l;
}

// fp32 [M][D] contiguous -> hi/lo planes [MPAD][D]; pad rows zeroed.
__global__ void split_x(const float* __restrict__ x, ushort* __restrict__ hi,
                        ushort* __restrict__ lo, long nvalid, long ntotal) {
    long i = ((long)blockIdx.x * blockDim.x + threadIdx.x) * 4;
    if (i >= ntotal) return;
    float4 v = {0.f, 0.f, 0.f, 0.f};
    if (i < nvalid) v = *(const float4*)(x + i);
    ushort4 h, l;
    split1(v.x, h.x, l.x); split1(v.y, h.y, l.y);
    split1(v.z, h.z, l.z); split1(v.w, h.w, l.w);
    *(ushort4*)(hi + i) = h; *(ushort4*)(lo + i) = l;
}

// ---------------------------------------------------------------------------
// Aggregations: mean over CSR neighbors; outputs hi/lo bf16 planes, pads zeroed
// ---------------------------------------------------------------------------
__global__ void agg128_f32(const float* __restrict__ x, const int* __restrict__ ptr,
                           const int* __restrict__ col, ushort* __restrict__ hi,
                           ushort* __restrict__ lo) {
    int g = blockIdx.x * blockDim.x + threadIdx.x;
    int node = g >> 5, l = g & 31;
    if (node >= MPAD) return;
    size_t ob = (size_t)node * 128 + l * 4;
    if (node >= NN) {
        *(ushort4*)(hi + ob) = make_ushort4(0, 0, 0, 0);
        *(ushort4*)(lo + ob) = make_ushort4(0, 0, 0, 0);
        return;
    }
    int p0 = ptr[node], p1 = ptr[node + 1];
    float4 a = {0.f, 0.f, 0.f, 0.f};
    for (int e = p0; e < p1; ++e) {
        float4 v = *(const float4*)(x + (size_t)col[e] * 128 + l * 4);
        a.x += v.x; a.y += v.y; a.z += v.z; a.w += v.w;
    }
    float inv = (p1 > p0) ? 1.0f / (float)(p1 - p0) : 0.0f;
    ushort4 h, lo4;
    split1(a.x * inv, h.x, lo4.x); split1(a.y * inv, h.y, lo4.y);
    split1(a.z * inv, h.z, lo4.z); split1(a.w * inv, h.w, lo4.w);
    *(ushort4*)(hi + ob) = h; *(ushort4*)(lo + ob) = lo4;
}

__global__ void agg256_pair(const ushort* __restrict__ xin_hi, const ushort* __restrict__ xin_lo,
                            const int* __restrict__ ptr, const int* __restrict__ col,
                            ushort* __restrict__ hi, ushort* __restrict__ lo) {
    int g = blockIdx.x * blockDim.x + threadIdx.x;
    int node = g >> 6, l = g & 63;
    if (node >= MPAD) return;
    size_t ob = (size_t)node * 256 + l * 4;
    if (node >= NN) {
        *(ushort4*)(hi + ob) = make_ushort4(0, 0, 0, 0);
        *(ushort4*)(lo + ob) = make_ushort4(0, 0, 0, 0);
        return;
    }
    int p0 = ptr[node], p1 = ptr[node + 1];
    float a0 = 0.f, a1 = 0.f, a2 = 0.f, a3 = 0.f;
    for (int e = p0; e < p1; ++e) {
        size_t sb = (size_t)col[e] * 256 + l * 4;
        ushort4 h4 = *(const ushort4*)(xin_hi + sb);
        ushort4 l4 = *(const ushort4*)(xin_lo + sb);
        a0 += bf2f(h4.x) + bf2f(l4.x);
        a1 += bf2f(h4.y) + bf2f(l4.y);
        a2 += bf2f(h4.z) + bf2f(l4.z);
        a3 += bf2f(h4.w) + bf2f(l4.w);
    }
    float inv = (p1 > p0) ? 1.0f / (float)(p1 - p0) : 0.0f;
    ushort4 h, lo4;
    split1(a0 * inv, h.x, lo4.x); split1(a1 * inv, h.y, lo4.y);
    split1(a2 * inv, h.z, lo4.z); split1(a3 * inv, h.w, lo4.w);
    *(ushort4*)(hi + ob) = h; *(ushort4*)(lo + ob) = lo4;
}

// ---------------------------------------------------------------------------
// Split-precision MFMA GEMM.
// C[MPAD,256] = sum_parts (Ahi+Alo)[M,K] @ (Whi+Wlo)[K,256]  (3-term split)
// A planes: [MPAD][K] bf16. W planes: TRANSPOSED [256][K] bf16.
// Block: 256 thr / 4 waves, tile 64(M) x 256(N), BK=32. Wave tile 64x64.
// A staged via global_load_lds (source-swizzled); W frags read from global (L2).
// ---------------------------------------------------------------------------
__global__ __launch_bounds__(256)
void gemm_split(const ushort* __restrict__ Ahi0, const ushort* __restrict__ Alo0,
                const ushort* __restrict__ Whi0, const ushort* __restrict__ Wlo0, int K0,
                const ushort* __restrict__ Ahi1, const ushort* __restrict__ Alo1,
                const ushort* __restrict__ Whi1, const ushort* __restrict__ Wlo1, int K1,
                const float* __restrict__ bias0, const float* __restrict__ bias1,
                float* __restrict__ Cf, ushort* __restrict__ Chi, ushort* __restrict__ Clo,
                int flags) {
    __shared__ ushort sAhi[64 * 32];
    __shared__ ushort sAlo[64 * 32];
    const int tid = threadIdx.x;
    const int m0 = blockIdx.x * 64;
    const int lane = tid & 63, wn = tid >> 6;
    const int fcol = lane & 15;            // free-index within 16
    const int fk = (lane >> 4) << 3;       // k offset 0,8,16,24
    // staging: lane covers LDS bytes tid*16 = row (tid>>2), chunk (tid&3);
    // source chunk XOR-swizzled so read-side swizzle spreads banks.
    const int srow = tid >> 2;
    const int schunk = (((tid & 3) ^ (srow & 3)) << 3);   // in ushorts
    // A frag read: row = mi*16+fcol, global chunk q=(lane>>4), slot=q^(row&3)
    const int aslot = (((lane >> 4) ^ (fcol & 3)) << 3);

    f32x4 acc[4][4];
    #pragma unroll
    for (int i = 0; i < 4; i++)
        #pragma unroll
        for (int j = 0; j < 4; j++) acc[i][j] = (f32x4){0.f, 0.f, 0.f, 0.f};

    auto dAhi = (__attribute__((address_space(3))) uint*)(sAhi + tid * 8);
    auto dAlo = (__attribute__((address_space(3))) uint*)(sAlo + tid * 8);

    #pragma unroll 1
    for (int part = 0; part < 2; ++part) {
        const ushort* Ahi = part ? Ahi1 : Ahi0;
        if (!Ahi) break;
        const ushort* Alo = part ? Alo1 : Alo0;
        const ushort* Whi = part ? Whi1 : Whi0;
        const ushort* Wlo = part ? Wlo1 : Wlo0;
        const int K = part ? K1 : K0;
        const ushort* pAhi = Ahi + (size_t)(m0 + srow) * K + schunk;
        const ushort* pAlo = Alo + (size_t)(m0 + srow) * K + schunk;
        size_t wbase[4];
        #pragma unroll
        for (int j = 0; j < 4; j++)
            wbase[j] = (size_t)(wn * 64 + j * 16 + fcol) * K + fk;

        #pragma unroll 1
        for (int k0 = 0; k0 < K; k0 += 32) {
            __builtin_amdgcn_global_load_lds(
                (const __attribute__((address_space(1))) uint*)(pAhi + k0), dAhi, 16, 0, 0);
            __builtin_amdgcn_global_load_lds(
                (const __attribute__((address_space(1))) uint*)(pAlo + k0), dAlo, 16, 0, 0);
            bf16x8 whi[4], wlo[4];
            #pragma unroll
            for (int j = 0; j < 4; j++) {
                whi[j] = *(const bf16x8*)(Whi + wbase[j] + k0);
                wlo[j] = *(const bf16x8*)(Wlo + wbase[j] + k0);
            }
            __syncthreads();
            bf16x8 ahi[4], alo[4];
            #pragma unroll
            for (int i = 0; i < 4; i++) {
                int off = ((i << 4) + fcol) * 32 + aslot;
                ahi[i] = *(const bf16x8*)(sAhi + off);
                alo[i] = *(const bf16x8*)(sAlo + off);
            }
            #pragma unroll
            for (int i = 0; i < 4; i++)
                #pragma unroll
                for (int j = 0; j < 4; j++) {
                    acc[i][j] = __builtin_amdgcn_mfma_f32_16x16x32_bf16(ahi[i], whi[j], acc[i][j], 0, 0, 0);
                    acc[i][j] = __builtin_amdgcn_mfma_f32_16x16x32_bf16(ahi[i], wlo[j], acc[i][j], 0, 0, 0);
                    acc[i][j] = __builtin_amdgcn_mfma_f32_16x16x32_bf16(alo[i], whi[j], acc[i][j], 0, 0, 0);
                }
            __syncthreads();
        }
    }

    const bool accf = flags & F_ACCF, relu = flags & F_RELU;
    const bool pairout = flags & F_PAIROUT, pairacc = flags & F_PAIRACC;
    float bb[4];
    #pragma unroll
    for (int j = 0; j < 4; j++) {
        int c = wn * 64 + j * 16 + fcol;
        float v = 0.f;
        if (bias0) v += bias0[c];
        if (bias1) v += bias1[c];
        bb[j] = v;
    }
    #pragma unroll
    for (int i = 0; i < 4; i++) {
        #pragma unroll
        for (int r = 0; r < 4; r++) {
            int gm = m0 + i * 16 + ((lane >> 4) << 2) + r;
            if (gm >= NN) continue;
            size_t rowb = (size_t)gm * 256;
            #pragma unroll
            for (int j = 0; j < 4; j++) {
                size_t idx = rowb + wn * 64 + j * 16 + fcol;
                float v = acc[i][j][r] + bb[j];
                if (accf) v += Cf[idx];
                if (pairacc) v += bf2f(Chi[idx]) + bf2f(Clo[idx]);
                if (relu) v = fmaxf(v, 0.f);
                if (pairout) {
                    ushort h, l; split1(v, h, l);
                    Chi[idx] = h; Clo[idx] = l;
                } else {
                    Cf[idx] = v;
                }
            }
        }
    }
}

// ---------------------------------------------------------------------------
extern "C" void kernel_launch(void* const* d_in, const int* in_sizes, int n_in,
                              void* d_out, int out_size, void* d_ws, size_t ws_size,
                              hipStream_t stream) {
    const float* x_user = (const float*)d_in[0];
    const float* x_item = (const float*)d_in[1];
    const int* src_rev  = (const int*)d_in[2];
    const int* dst_rev  = (const int*)d_in[3];
    const int* src_ab   = (const int*)d_in[4];
    const int* dst_ab   = (const int*)d_in[5];
    const float* Wl1_rev  = (const float*)d_in[6];
    const float* Wr1_rev  = (const float*)d_in[7];
    const float* b1_rev   = (const float*)d_in[8];
    const float* Wl1_rrev = (const float*)d_in[9];
    const float* Wr1_rrev = (const float*)d_in[10];
    const float* b1_rrev  = (const float*)d_in[11];
    const float* Wl1_ab   = (const float*)d_in[12];
    const float* Wr1_ab   = (const float*)d_in[13];
    const float* b1_ab    = (const float*)d_in[14];
    const float* Wl2_rev  = (const float*)d_in[15];
    const float* Wr2_rev  = (const float*)d_in[16];
    const float* b2_rev   = (const float*)d_in[17];
    const float* Wl2_rrev = (const float*)d_in[18];
    const float* Wr2_rrev = (const float*)d_in[19];
    const float* b2_rrev  = (const float*)d_in[20];
    const float* Wl2_ab   = (const float*)d_in[21];
    const float* Wr2_ab   = (const float*)d_in[22];
    const float* b2_ab    = (const float*)d_in[23];

    float* o_user = (float*)d_out;
    float* o_item = (float*)d_out + (size_t)NN * 256;

    char* ws = (char*)d_ws;
    size_t off = 0;
    auto alloc = [&](size_t bytes) -> void* {
        void* p = ws + off;
        off += (bytes + 255) & ~(size_t)255;
        return p;
    };
    const size_t P256 = (size_t)MPAD * 256 * 2;   // bf16 plane, 256 wide
    const size_t P128 = (size_t)MPAD * 128 * 2;
    ushort* slab_hi = (ushort*)alloc(P256);
    ushort* slab_lo = (ushort*)alloc(P256);
    ushort* hI_hi   = (ushort*)alloc(P256);
    ushort* hI_lo   = (ushort*)alloc(P256);
    ushort* hU_hi   = (ushort*)alloc(P256);
    ushort* hU_lo   = (ushort*)alloc(P256);
    ushort* xu_hi   = (ushort*)alloc(P128);
    ushort* xu_lo   = (ushort*)alloc(P128);
    ushort* xi_hi   = (ushort*)alloc(P128);
    ushort* xi_lo   = (ushort*)alloc(P128);
    const size_t W1SZ = 128 * 256 * 2, W2SZ = 256 * 256 * 2;
    ushort* wt_l1rev_h  = (ushort*)alloc(W1SZ); ushort* wt_l1rev_l  = (ushort*)alloc(W1SZ);
    ushort* wt_l1ab_h   = (ushort*)alloc(W1SZ); ushort* wt_l1ab_l   = (ushort*)alloc(W1SZ);
    ushort* wt_l1rrev_h = (ushort*)alloc(W1SZ); ushort* wt_l1rrev_l = (ushort*)alloc(W1SZ);
    ushort* wt_r1c_h    = (ushort*)alloc(W1SZ); ushort* wt_r1c_l    = (ushort*)alloc(W1SZ);
    ushort* wt_r1rrev_h = (ushort*)alloc(W1SZ); ushort* wt_r1rrev_l = (ushort*)alloc(W1SZ);
    ushort* wt_l2rev_h  = (ushort*)alloc(W2SZ); ushort* wt_l2rev_l  = (ushort*)alloc(W2SZ);
    ushort* wt_l2ab_h   = (ushort*)alloc(W2SZ); ushort* wt_l2ab_l   = (ushort*)alloc(W2SZ);
    ushort* wt_l2rrev_h = (ushort*)alloc(W2SZ); ushort* wt_l2rrev_l = (ushort*)alloc(W2SZ);
    ushort* wt_r2c_h    = (ushort*)alloc(W2SZ); ushort* wt_r2c_l    = (ushort*)alloc(W2SZ);
    ushort* wt_r2rrev_h = (ushort*)alloc(W2SZ); ushort* wt_r2rrev_l = (ushort*)alloc(W2SZ);
    int* ptrA = (int*)alloc((NN + 1) * 4);
    int* ptrB = (int*)alloc((NN + 1) * 4);
    int* ptrC = (int*)alloc((NN + 1) * 4);
    int* colA = (int*)alloc((size_t)ER_ * 4);
    int* colB = (int*)alloc((size_t)EA_ * 4);
    int* colC = (int*)alloc((size_t)ER_ * 4);
    int* curA = (int*)alloc((size_t)3 * NN * 4);
    int* curB = curA + NN;
    int* curC = curA + 2 * NN;

    const int TPB = 256;
    dim3 egrid((ER_ + TPB - 1) / TPB);

    // CSR build
    hipMemsetAsync(curA, 0, (size_t)3 * NN * 4, stream);
    count_deg<<<egrid, TPB, 0, stream>>>(dst_rev, ER_, curA);
    count_deg<<<egrid, TPB, 0, stream>>>(dst_ab,  EA_, curB);
    count_deg<<<egrid, TPB, 0, stream>>>(src_rev, ER_, curC);
    exscan3<<<3, 1024, 0, stream>>>(curA, ptrA, curB, ptrB, curC, ptrC, NN);
    hipMemsetAsync(curA, 0, (size_t)3 * NN * 4, stream);
    fill_csr<<<egrid, TPB, 0, stream>>>(dst_rev, src_rev, ER_, ptrA, curA, colA);
    fill_csr<<<egrid, TPB, 0, stream>>>(dst_ab,  src_ab,  EA_, ptrB, curB, colB);
    fill_csr<<<egrid, TPB, 0, stream>>>(src_rev, dst_rev, ER_, ptrC, curC, colC);

    // weight prep (transpose + hi/lo split)
    dim3 wg1((128 * 256 + TPB - 1) / TPB), wg2((256 * 256 + TPB - 1) / TPB);
    wprep<<<wg1, TPB, 0, stream>>>(Wl1_rev,  nullptr, 128, wt_l1rev_h,  wt_l1rev_l);
    wprep<<<wg1, TPB, 0, stream>>>(Wl1_ab,   nullptr, 128, wt_l1ab_h,   wt_l1ab_l);
    wprep<<<wg1, TPB, 0, stream>>>(Wl1_rrev, nullptr, 128, wt_l1rrev_h, wt_l1rrev_l);
    wprep<<<wg1, TPB, 0, stream>>>(Wr1_rev,  Wr1_ab,  128, wt_r1c_h,    wt_r1c_l);
    wprep<<<wg1, TPB, 0, stream>>>(Wr1_rrev, nullptr, 128, wt_r1rrev_h, wt_r1rrev_l);
    wprep<<<wg2, TPB, 0, stream>>>(Wl2_rev,  nullptr, 256, wt_l2rev_h,  wt_l2rev_l);
    wprep<<<wg2, TPB, 0, stream>>>(Wl2_ab,   nullptr, 256, wt_l2ab_h,   wt_l2ab_l);
    wprep<<<wg2, TPB, 0, stream>>>(Wl2_rrev, nullptr, 256, wt_l2rrev_h, wt_l2rrev_l);
    wprep<<<wg2, TPB, 0, stream>>>(Wr2_rev,  Wr2_ab,  256, wt_r2c_h,    wt_r2c_l);
    wprep<<<wg2, TPB, 0, stream>>>(Wr2_rrev, nullptr, 256, wt_r2rrev_h, wt_r2rrev_l);

    // x splits
    long n128v = (long)NN * 128, n128t = (long)MPAD * 128;
    dim3 sxg((n128t / 4 + TPB - 1) / TPB);
    split_x<<<sxg, TPB, 0, stream>>>(x_user, xu_hi, xu_lo, n128v, n128t);
    split_x<<<sxg, TPB, 0, stream>>>(x_item, xi_hi, xi_lo, n128v, n128t);

    dim3 a128g((size_t)MPAD * 32 / TPB), a256g((size_t)MPAD * 64 / TPB);
    dim3 ggrid(MPAD / 64);

    // ---- layer 1 ----
    agg128_f32<<<a128g, TPB, 0, stream>>>(x_user, ptrA, colA, slab_hi, slab_lo);
    gemm_split<<<ggrid, TPB, 0, stream>>>(slab_hi, slab_lo, wt_l1rev_h, wt_l1rev_l, 128,
                                          xi_hi, xi_lo, wt_r1c_h, wt_r1c_l, 128,
                                          b1_rev, b1_ab, nullptr, hI_hi, hI_lo, F_PAIROUT);
    agg128_f32<<<a128g, TPB, 0, stream>>>(x_item, ptrB, colB, slab_hi, slab_lo);
    gemm_split<<<ggrid, TPB, 0, stream>>>(slab_hi, slab_lo, wt_l1ab_h, wt_l1ab_l, 128,
                                          nullptr, nullptr, nullptr, nullptr, 0,
                                          nullptr, nullptr, nullptr, hI_hi, hI_lo,
                                          F_PAIROUT | F_PAIRACC | F_RELU);
    agg128_f32<<<a128g, TPB, 0, stream>>>(x_item, ptrC, colC, slab_hi, slab_lo);
    gemm_split<<<ggrid, TPB, 0, stream>>>(slab_hi, slab_lo, wt_l1rrev_h, wt_l1rrev_l, 128,
                                          xu_hi, xu_lo, wt_r1rrev_h, wt_r1rrev_l, 128,
                                          b1_rrev, nullptr, nullptr, hU_hi, hU_lo,
                                          F_PAIROUT | F_RELU);

    // ---- layer 2 ----
    agg256_pair<<<a256g, TPB, 0, stream>>>(hU_hi, hU_lo, ptrA, colA, slab_hi, slab_lo);
    gemm_split<<<ggrid, TPB, 0, stream>>>(slab_hi, slab_lo, wt_l2rev_h, wt_l2rev_l, 256,
                                          hI_hi, hI_lo, wt_r2c_h, wt_r2c_l, 256,
                                          b2_rev, b2_ab, o_item, nullptr, nullptr, 0);
    agg256_pair<<<a256g, TPB, 0, stream>>>(hI_hi, hI_lo, ptrB, colB, slab_hi, slab_lo);
    gemm_split<<<ggrid, TPB, 0, stream>>>(slab_hi, slab_lo, wt_l2ab_h, wt_l2ab_l, 256,
                                          nullptr, nullptr, nullptr, nullptr, 0,
                                          nullptr, nullptr, o_item, nullptr, nullptr, F_ACCF);
    agg256_pair<<<a256g, TPB, 0, stream>>>(hI_hi, hI_lo, ptrC, colC, slab_hi, slab_lo);
    gemm_split<<<ggrid, TPB, 0, stream>>>(slab_hi, slab_lo, wt_l2rrev_h, wt_l2rrev_l, 256,
                                          hU_hi, hU_lo, wt_r2rrev_h, wt_r2rrev_l, 256,
                                          b2_rrev, nullptr, o_user, nullptr, nullptr, 0);
}

// Round 4
// 1512.579 us; speedup vs baseline: 1.5443x; 1.1217x over previous
//
#include <hip/hip_runtime.h>
#include <hip/hip_bf16.h>

#define NN    100000
#define MPAD  100096          // 1564 * 64, >= NN, padded rows zeroed/ignored
#define ER_   500000
#define EA_   500000

#define F_RELU    2
#define F_PAIROUT 4

typedef __attribute__((ext_vector_type(8))) short bf16x8;
typedef __attribute__((ext_vector_type(4))) float f32x4;
typedef __attribute__((address_space(3))) uint lds_uint;
typedef const __attribute__((address_space(1))) uint g_uint;

__device__ __forceinline__ ushort f2bf(float f) {
    union { __hip_bfloat16 h; ushort u; } c; c.h = __float2bfloat16(f); return c.u;
}
__device__ __forceinline__ float bf2f(ushort u) {
    union { ushort u; __hip_bfloat16 h; } c; c.u = u; return __bfloat162float(c.h);
}
__device__ __forceinline__ void split1(float v, ushort& h, ushort& l) {
    h = f2bf(v); l = f2bf(v - bf2f(h));
}

// ---------------------------------------------------------------------------
// CSR build
// ---------------------------------------------------------------------------
__global__ void count_deg(const int* __restrict__ dst, int n_edges, int* __restrict__ cnt) {
    int i = blockIdx.x * blockDim.x + threadIdx.x;
    if (i < n_edges) atomicAdd(&cnt[dst[i]], 1);
}

__global__ void fill_csr(const int* __restrict__ dst, const int* __restrict__ src, int n_edges,
                         const int* __restrict__ ptr, int* __restrict__ cur, int* __restrict__ col) {
    int i = blockIdx.x * blockDim.x + threadIdx.x;
    if (i < n_edges) {
        int d = dst[i];
        int slot = ptr[d] + atomicAdd(&cur[d], 1);
        col[slot] = src[i];
    }
}

__global__ void exscan3(const int* __restrict__ c0, int* __restrict__ p0,
                        const int* __restrict__ c1, int* __restrict__ p1,
                        const int* __restrict__ c2, int* __restrict__ p2, int n) {
    const int* cnt = (blockIdx.x == 0) ? c0 : (blockIdx.x == 1) ? c1 : c2;
    int*       ptr = (blockIdx.x == 0) ? p0 : (blockIdx.x == 1) ? p1 : p2;
    __shared__ int wsum[16];
    __shared__ int s_carry, s_tot;
    int tid = threadIdx.x, lane = tid & 63, wid = tid >> 6;
    if (tid == 0) s_carry = 0;
    __syncthreads();
    for (int base = 0; base < n; base += 4096) {
        int i0 = base + tid * 4;
        int4 v = {0, 0, 0, 0};
        if (i0 + 3 < n) v = *(const int4*)(cnt + i0);
        else {
            if (i0     < n) v.x = cnt[i0];
            if (i0 + 1 < n) v.y = cnt[i0 + 1];
            if (i0 + 2 < n) v.z = cnt[i0 + 2];
        }
        int s = v.x + v.y + v.z + v.w;
        int isc = s;
        #pragma unroll
        for (int off = 1; off < 64; off <<= 1) {
            int t = __shfl_up(isc, off, 64);
            if (lane >= off) isc += t;
        }
        if (lane == 63) wsum[wid] = isc;
        __syncthreads();
        if (wid == 0) {
            int w = (lane < 16) ? wsum[lane] : 0;
            int wsc = w;
            #pragma unroll
            for (int off = 1; off < 16; off <<= 1) {
                int t = __shfl_up(wsc, off, 64);
                if (lane >= off) wsc += t;
            }
            if (lane < 16) wsum[lane] = wsc - w;
            if (lane == 15) s_tot = wsc;
        }
        __syncthreads();
        int excl = s_carry + wsum[wid] + (isc - s);
        if (i0     < n) ptr[i0]     = excl;
        if (i0 + 1 < n) ptr[i0 + 1] = excl + v.x;
        if (i0 + 2 < n) ptr[i0 + 2] = excl + v.x + v.y;
        if (i0 + 3 < n) ptr[i0 + 3] = excl + v.x + v.y + v.z;
        __syncthreads();
        if (tid == 0) s_carry += s_tot;
        __syncthreads();
    }
    if (tid == 0) ptr[n] = s_carry;
}

// ---------------------------------------------------------------------------
// Weight prep: W[K][256] fp32 (+ optional addend) -> transposed hi/lo bf16
// ---------------------------------------------------------------------------
__global__ void wprep(const float* __restrict__ W0, const float* __restrict__ W1, int K,
                      ushort* __restrict__ hiT, ushort* __restrict__ loT) {
    int i = blockIdx.x * blockDim.x + threadIdx.x;
    if (i >= K * 256) return;
    int k = i >> 8, n = i & 255;
    float v = W0[i];
    if (W1) v += W1[i];
    ushort h, l; split1(v, h, l);
    hiT[n * K + k] = h; loT[n * K + k] = l;
}

// fp32 [M][D] contiguous -> hi/lo planes [MPAD][D]; pad rows zeroed.
__global__ void split_x(const float* __restrict__ x, ushort* __restrict__ hi,
                        ushort* __restrict__ lo, long nvalid, long ntotal) {
    long i = ((long)blockIdx.x * blockDim.x + threadIdx.x) * 4;
    if (i >= ntotal) return;
    float4 v = {0.f, 0.f, 0.f, 0.f};
    if (i < nvalid) v = *(const float4*)(x + i);
    ushort4 h, l;
    split1(v.x, h.x, l.x); split1(v.y, h.y, l.y);
    split1(v.z, h.z, l.z); split1(v.w, h.w, l.w);
    *(ushort4*)(hi + i) = h; *(ushort4*)(lo + i) = l;
}

// ---------------------------------------------------------------------------
// Aggregations
// ---------------------------------------------------------------------------
__global__ void agg128_f32(const float* __restrict__ x, const int* __restrict__ ptr,
                           const int* __restrict__ col, ushort* __restrict__ hi,
                           ushort* __restrict__ lo) {
    int g = blockIdx.x * blockDim.x + threadIdx.x;
    int node = g >> 5, l = g & 31;
    if (node >= MPAD) return;
    size_t ob = (size_t)node * 128 + l * 4;
    if (node >= NN) {
        *(ushort4*)(hi + ob) = make_ushort4(0, 0, 0, 0);
        *(ushort4*)(lo + ob) = make_ushort4(0, 0, 0, 0);
        return;
    }
    int p0 = ptr[node], p1 = ptr[node + 1];
    float4 a = {0.f, 0.f, 0.f, 0.f};
    for (int e = p0; e < p1; ++e) {
        float4 v = *(const float4*)(x + (size_t)col[e] * 128 + l * 4);
        a.x += v.x; a.y += v.y; a.z += v.z; a.w += v.w;
    }
    float inv = (p1 > p0) ? 1.0f / (float)(p1 - p0) : 0.0f;
    ushort4 h, lo4;
    split1(a.x * inv, h.x, lo4.x); split1(a.y * inv, h.y, lo4.y);
    split1(a.z * inv, h.z, lo4.z); split1(a.w * inv, h.w, lo4.w);
    *(ushort4*)(hi + ob) = h; *(ushort4*)(lo + ob) = lo4;
}

__global__ void agg256_pair(const ushort* __restrict__ xin_hi, const ushort* __restrict__ xin_lo,
                            const int* __restrict__ ptr, const int* __restrict__ col,
                            ushort* __restrict__ hi, ushort* __restrict__ lo) {
    int g = blockIdx.x * blockDim.x + threadIdx.x;
    int node = g >> 6, l = g & 63;
    if (node >= MPAD) return;
    size_t ob = (size_t)node * 256 + l * 4;
    if (node >= NN) {
        *(ushort4*)(hi + ob) = make_ushort4(0, 0, 0, 0);
        *(ushort4*)(lo + ob) = make_ushort4(0, 0, 0, 0);
        return;
    }
    int p0 = ptr[node], p1 = ptr[node + 1];
    float a0 = 0.f, a1 = 0.f, a2 = 0.f, a3 = 0.f;
    for (int e = p0; e < p1; ++e) {
        size_t sb = (size_t)col[e] * 256 + l * 4;
        ushort4 h4 = *(const ushort4*)(xin_hi + sb);
        ushort4 l4 = *(const ushort4*)(xin_lo + sb);
        a0 += bf2f(h4.x) + bf2f(l4.x);
        a1 += bf2f(h4.y) + bf2f(l4.y);
        a2 += bf2f(h4.z) + bf2f(l4.z);
        a3 += bf2f(h4.w) + bf2f(l4.w);
    }
    float inv = (p1 > p0) ? 1.0f / (float)(p1 - p0) : 0.0f;
    ushort4 h, lo4;
    split1(a0 * inv, h.x, lo4.x); split1(a1 * inv, h.y, lo4.y);
    split1(a2 * inv, h.z, lo4.z); split1(a3 * inv, h.w, lo4.w);
    *(ushort4*)(hi + ob) = h; *(ushort4*)(lo + ob) = lo4;
}

// ---------------------------------------------------------------------------
// Split-precision MFMA GEMM, up to 3 fused parts, 2-phase prefetch.
// C[MPAD,256] = sum_p (Ahi_p+Alo_p)[M,Kp] @ (Whi_p+Wlo_p)[Kp,256]
// A planes [MPAD][K] bf16; W planes transposed [256][K] bf16.
// Block 256 thr / 4 waves; tile 64(M) x 256(N); BK=32; wave tile 64x64.
// Steps linearized across parts; LDS A double-buffered; W frags reg-dbuf;
// STAGE(t+1)+Wload(t+1) issued BEFORE compute(t), drained at next barrier.
// ---------------------------------------------------------------------------
struct GParts {
    const ushort *Ah0, *Al0, *Wh0, *Wl0;
    const ushort *Ah1, *Al1, *Wh1, *Wl1;
    const ushort *Ah2, *Al2, *Wh2, *Wl2;
    int ksh0, ksh1, ksh2;   // log2(K) per part
    int c1, c2, S;          // cumulative step ends (part0: [0,c1), part1: [c1,c2), part2: [c2,S))
};

__global__ __launch_bounds__(256, 2)
void gemm_split(GParts P, const float* __restrict__ bias0, const float* __restrict__ bias1,
                float* __restrict__ Cf, ushort* __restrict__ Chi, ushort* __restrict__ Clo,
                int flags) {
    __shared__ ushort sH0[64 * 32], sL0[64 * 32], sH1[64 * 32], sL1[64 * 32];
    const int tid = threadIdx.x;
    const int m0 = blockIdx.x * 64;
    const int lane = tid & 63, wn = tid >> 6;
    const int fcol = lane & 15;            // free index within 16
    const int fk = (lane >> 4) << 3;       // k offset 0,8,16,24
    const int srow = tid >> 2;             // staging row 0..63
    const int schunk = (((tid & 3) ^ (srow & 3)) << 3);   // source swizzle (ushorts)
    const int aslot = (((lane >> 4) ^ (fcol & 3)) << 3);  // read-side swizzle

    f32x4 acc[4][4];
    #pragma unroll
    for (int i = 0; i < 4; i++)
        #pragma unroll
        for (int j = 0; j < 4; j++) acc[i][j] = (f32x4){0.f, 0.f, 0.f, 0.f};

    lds_uint* dH0 = (lds_uint*)(sH0 + tid * 8);
    lds_uint* dL0 = (lds_uint*)(sL0 + tid * 8);
    lds_uint* dH1 = (lds_uint*)(sH1 + tid * 8);
    lds_uint* dL1 = (lds_uint*)(sL1 + tid * 8);

    // step -> (part pointers, k-offset); s uniform, all selects scalar
    auto pick = [&](int s, const ushort*& ah, const ushort*& al,
                    const ushort*& wh, const ushort*& wl, int& ksh, int& k0) {
        s = (s < P.S) ? s : (P.S - 1);
        int p = (s >= P.c1) + (s >= P.c2);
        ah = (p == 2) ? P.Ah2 : (p == 1) ? P.Ah1 : P.Ah0;
        al = (p == 2) ? P.Al2 : (p == 1) ? P.Al1 : P.Al0;
        wh = (p == 2) ? P.Wh2 : (p == 1) ? P.Wh1 : P.Wh0;
        wl = (p == 2) ? P.Wl2 : (p == 1) ? P.Wl1 : P.Wl0;
        ksh = (p == 2) ? P.ksh2 : (p == 1) ? P.ksh1 : P.ksh0;
        int base = (p == 2) ? P.c2 : (p == 1) ? P.c1 : 0;
        k0 = (s - base) << 5;
    };

    auto stage = [&](int s, lds_uint* dh, lds_uint* dl) {
        const ushort *ah, *al, *wh, *wl; int ksh, k0;
        pick(s, ah, al, wh, wl, ksh, k0);
        size_t ro = ((size_t)(m0 + srow) << ksh) + schunk + k0;
        __builtin_amdgcn_global_load_lds((g_uint*)(ah + ro), dh, 16, 0, 0);
        __builtin_amdgcn_global_load_lds((g_uint*)(al + ro), dl, 16, 0, 0);
    };

    struct WF { bf16x8 h[4], l[4]; };
    auto wload = [&](int s, WF& w) {
        const ushort *ah, *al, *wh, *wl; int ksh, k0;
        pick(s, ah, al, wh, wl, ksh, k0);
        int colb = wn * 64 + fcol;
        #pragma unroll
        for (int j = 0; j < 4; j++) {
            size_t off = ((size_t)(colb + j * 16) << ksh) + fk + k0;
            w.h[j] = *(const bf16x8*)(wh + off);
            w.l[j] = *(const bf16x8*)(wl + off);
        }
    };

    auto compute = [&](const ushort* sh, const ushort* sl, const WF& w) {
        bf16x8 ah[4], al[4];
        #pragma unroll
        for (int i = 0; i < 4; i++) {
            int off = ((i << 4) + fcol) * 32 + aslot;
            ah[i] = *(const bf16x8*)(sh + off);
            al[i] = *(const bf16x8*)(sl + off);
        }
        #pragma unroll
        for (int i = 0; i < 4; i++)
            #pragma unroll
            for (int j = 0; j < 4; j++) {
                acc[i][j] = __builtin_amdgcn_mfma_f32_16x16x32_bf16(ah[i], w.h[j], acc[i][j], 0, 0, 0);
                acc[i][j] = __builtin_amdgcn_mfma_f32_16x16x32_bf16(ah[i], w.l[j], acc[i][j], 0, 0, 0);
                acc[i][j] = __builtin_amdgcn_mfma_f32_16x16x32_bf16(al[i], w.h[j], acc[i][j], 0, 0, 0);
            }
    };

    WF wA, wB;
    stage(0, dH0, dL0);
    wload(0, wA);
    #pragma unroll 1
    for (int t = 0; t < P.S; t += 2) {
        __syncthreads();                 // drains stage(t)+wload(t)
        stage(t + 1, dH1, dL1);
        wload(t + 1, wB);
        compute(sH0, sL0, wA);
        __syncthreads();                 // drains stage(t+1)+wload(t+1)
        stage(t + 2, dH0, dL0);          // phantom-clamped at end: harmless
        wload(t + 2, wA);
        compute(sH1, sL1, wB);
    }

    const bool relu = flags & F_RELU, pairout = flags & F_PAIROUT;
    float bb[4];
    #pragma unroll
    for (int j = 0; j < 4; j++) {
        int c = wn * 64 + j * 16 + fcol;
        float v = 0.f;
        if (bias0) v += bias0[c];
        if (bias1) v += bias1[c];
        bb[j] = v;
    }
    #pragma unroll
    for (int i = 0; i < 4; i++) {
        #pragma unroll
        for (int r = 0; r < 4; r++) {
            int gm = m0 + i * 16 + ((lane >> 4) << 2) + r;
            if (gm >= NN) continue;
            size_t rowb = (size_t)gm * 256;
            #pragma unroll
            for (int j = 0; j < 4; j++) {
                size_t idx = rowb + wn * 64 + j * 16 + fcol;
                float v = acc[i][j][r] + bb[j];
                if (relu) v = fmaxf(v, 0.f);
                if (pairout) {
                    ushort h, l; split1(v, h, l);
                    Chi[idx] = h; Clo[idx] = l;
                } else {
                    Cf[idx] = v;
                }
            }
        }
    }
}

// ---------------------------------------------------------------------------
extern "C" void kernel_launch(void* const* d_in, const int* in_sizes, int n_in,
                              void* d_out, int out_size, void* d_ws, size_t ws_size,
                              hipStream_t stream) {
    const float* x_user = (const float*)d_in[0];
    const float* x_item = (const float*)d_in[1];
    const int* src_rev  = (const int*)d_in[2];
    const int* dst_rev  = (const int*)d_in[3];
    const int* src_ab   = (const int*)d_in[4];
    const int* dst_ab   = (const int*)d_in[5];
    const float* Wl1_rev  = (const float*)d_in[6];
    const float* Wr1_rev  = (const float*)d_in[7];
    const float* b1_rev   = (const float*)d_in[8];
    const float* Wl1_rrev = (const float*)d_in[9];
    const float* Wr1_rrev = (const float*)d_in[10];
    const float* b1_rrev  = (const float*)d_in[11];
    const float* Wl1_ab   = (const float*)d_in[12];
    const float* Wr1_ab   = (const float*)d_in[13];
    const float* b1_ab    = (const float*)d_in[14];
    const float* Wl2_rev  = (const float*)d_in[15];
    const float* Wr2_rev  = (const float*)d_in[16];
    const float* b2_rev   = (const float*)d_in[17];
    const float* Wl2_rrev = (const float*)d_in[18];
    const float* Wr2_rrev = (const float*)d_in[19];
    const float* b2_rrev  = (const float*)d_in[20];
    const float* Wl2_ab   = (const float*)d_in[21];
    const float* Wr2_ab   = (const float*)d_in[22];
    const float* b2_ab    = (const float*)d_in[23];

    float* o_user = (float*)d_out;
    float* o_item = (float*)d_out + (size_t)NN * 256;

    char* ws = (char*)d_ws;
    size_t off = 0;
    auto alloc = [&](size_t bytes) -> void* {
        void* p = ws + off;
        off += (bytes + 255) & ~(size_t)255;
        return p;
    };
    const size_t P256 = (size_t)MPAD * 256 * 2;   // bf16 plane bytes (256 wide)
    const size_t P128 = (size_t)MPAD * 128 * 2;
    ushort* slab_hi = (ushort*)alloc(P256);
    ushort* slab_lo = (ushort*)alloc(P256);
    ushort* hI_hi   = (ushort*)alloc(P256);
    ushort* hI_lo   = (ushort*)alloc(P256);
    ushort* hU_hi   = (ushort*)alloc(P256);
    ushort* hU_lo   = (ushort*)alloc(P256);
    ushort* xu_hi   = (ushort*)alloc(P128);
    ushort* xu_lo   = (ushort*)alloc(P128);
    ushort* xi_hi   = (ushort*)alloc(P128);
    ushort* xi_lo   = (ushort*)alloc(P128);
    // slab2 aliases (dead ranges at time of use):
    ushort* s2L1_hi = hU_hi;   // layer-1: hU not yet written
    ushort* s2L1_lo = hU_lo;
    ushort* s2L2_hi = xu_hi;   // layer-2: xu/xi dead; spans xu_hi+xu_lo (2*P128 = P256)
    ushort* s2L2_lo = xi_hi;   // spans xi_hi+xi_lo
    const size_t W1SZ = 128 * 256 * 2, W2SZ = 256 * 256 * 2;
    ushort* wt_l1rev_h  = (ushort*)alloc(W1SZ); ushort* wt_l1rev_l  = (ushort*)alloc(W1SZ);
    ushort* wt_l1ab_h   = (ushort*)alloc(W1SZ); ushort* wt_l1ab_l   = (ushort*)alloc(W1SZ);
    ushort* wt_l1rrev_h = (ushort*)alloc(W1SZ); ushort* wt_l1rrev_l = (ushort*)alloc(W1SZ);
    ushort* wt_r1c_h    = (ushort*)alloc(W1SZ); ushort* wt_r1c_l    = (ushort*)alloc(W1SZ);
    ushort* wt_r1rrev_h = (ushort*)alloc(W1SZ); ushort* wt_r1rrev_l = (ushort*)alloc(W1SZ);
    ushort* wt_l2rev_h  = (ushort*)alloc(W2SZ); ushort* wt_l2rev_l  = (ushort*)alloc(W2SZ);
    ushort* wt_l2ab_h   = (ushort*)alloc(W2SZ); ushort* wt_l2ab_l   = (ushort*)alloc(W2SZ);
    ushort* wt_l2rrev_h = (ushort*)alloc(W2SZ); ushort* wt_l2rrev_l = (ushort*)alloc(W2SZ);
    ushort* wt_r2c_h    = (ushort*)alloc(W2SZ); ushort* wt_r2c_l    = (ushort*)alloc(W2SZ);
    ushort* wt_r2rrev_h = (ushort*)alloc(W2SZ); ushort* wt_r2rrev_l = (ushort*)alloc(W2SZ);
    int* ptrA = (int*)alloc((NN + 1) * 4);
    int* ptrB = (int*)alloc((NN + 1) * 4);
    int* ptrC = (int*)alloc((NN + 1) * 4);
    int* colA = (int*)alloc((size_t)ER_ * 4);
    int* colB = (int*)alloc((size_t)EA_ * 4);
    int* colC = (int*)alloc((size_t)ER_ * 4);
    int* curA = (int*)alloc((size_t)3 * NN * 4);
    int* curB = curA + NN;
    int* curC = curA + 2 * NN;

    const int TPB = 256;
    dim3 egrid((ER_ + TPB - 1) / TPB);

    // CSR build
    hipMemsetAsync(curA, 0, (size_t)3 * NN * 4, stream);
    count_deg<<<egrid, TPB, 0, stream>>>(dst_rev, ER_, curA);
    count_deg<<<egrid, TPB, 0, stream>>>(dst_ab,  EA_, curB);
    count_deg<<<egrid, TPB, 0, stream>>>(src_rev, ER_, curC);
    exscan3<<<3, 1024, 0, stream>>>(curA, ptrA, curB, ptrB, curC, ptrC, NN);
    hipMemsetAsync(curA, 0, (size_t)3 * NN * 4, stream);
    fill_csr<<<egrid, TPB, 0, stream>>>(dst_rev, src_rev, ER_, ptrA, curA, colA);
    fill_csr<<<egrid, TPB, 0, stream>>>(dst_ab,  src_ab,  EA_, ptrB, curB, colB);
    fill_csr<<<egrid, TPB, 0, stream>>>(src_rev, dst_rev, ER_, ptrC, curC, colC);

    // weight prep
    dim3 wg1((128 * 256 + TPB - 1) / TPB), wg2((256 * 256 + TPB - 1) / TPB);
    wprep<<<wg1, TPB, 0, stream>>>(Wl1_rev,  nullptr, 128, wt_l1rev_h,  wt_l1rev_l);
    wprep<<<wg1, TPB, 0, stream>>>(Wl1_ab,   nullptr, 128, wt_l1ab_h,   wt_l1ab_l);
    wprep<<<wg1, TPB, 0, stream>>>(Wl1_rrev, nullptr, 128, wt_l1rrev_h, wt_l1rrev_l);
    wprep<<<wg1, TPB, 0, stream>>>(Wr1_rev,  Wr1_ab,  128, wt_r1c_h,    wt_r1c_l);
    wprep<<<wg1, TPB, 0, stream>>>(Wr1_rrev, nullptr, 128, wt_r1rrev_h, wt_r1rrev_l);
    wprep<<<wg2, TPB, 0, stream>>>(Wl2_rev,  nullptr, 256, wt_l2rev_h,  wt_l2rev_l);
    wprep<<<wg2, TPB, 0, stream>>>(Wl2_ab,   nullptr, 256, wt_l2ab_h,   wt_l2ab_l);
    wprep<<<wg2, TPB, 0, stream>>>(Wl2_rrev, nullptr, 256, wt_l2rrev_h, wt_l2rrev_l);
    wprep<<<wg2, TPB, 0, stream>>>(Wr2_rev,  Wr2_ab,  256, wt_r2c_h,    wt_r2c_l);
    wprep<<<wg2, TPB, 0, stream>>>(Wr2_rrev, nullptr, 256, wt_r2rrev_h, wt_r2rrev_l);

    // x splits
    long n128v = (long)NN * 128, n128t = (long)MPAD * 128;
    dim3 sxg((n128t / 4 + TPB - 1) / TPB);
    split_x<<<sxg, TPB, 0, stream>>>(x_user, xu_hi, xu_lo, n128v, n128t);
    split_x<<<sxg, TPB, 0, stream>>>(x_item, xi_hi, xi_lo, n128v, n128t);

    dim3 a128g((size_t)MPAD * 32 / TPB), a256g((size_t)MPAD * 64 / TPB);
    dim3 ggrid(MPAD / 64);

    auto launch_gemm = [&](const ushort* a0h, const ushort* a0l, const ushort* w0h, const ushort* w0l, int K0,
                           const ushort* a1h, const ushort* a1l, const ushort* w1h, const ushort* w1l, int K1,
                           const ushort* a2h, const ushort* a2l, const ushort* w2h, const ushort* w2l, int K2,
                           const float* bias0, const float* bias1,
                           float* cf, ushort* chi, ushort* clo, int flags) {
        GParts P;
        P.Ah0 = a0h; P.Al0 = a0l; P.Wh0 = w0h; P.Wl0 = w0l;
        P.Ah1 = a1h ? a1h : a0h; P.Al1 = a1l ? a1l : a0l;
        P.Wh1 = w1h ? w1h : w0h; P.Wl1 = w1l ? w1l : w0l;
        P.Ah2 = a2h ? a2h : a0h; P.Al2 = a2l ? a2l : a0l;
        P.Wh2 = w2h ? w2h : w0h; P.Wl2 = w2l ? w2l : w0l;
        P.ksh0 = (K0 == 256) ? 8 : 7;
        P.ksh1 = (K1 == 256) ? 8 : 7;
        P.ksh2 = (K2 == 256) ? 8 : 7;
        P.c1 = K0 >> 5; P.c2 = P.c1 + (K1 >> 5); P.S = P.c2 + (K2 >> 5);
        gemm_split<<<ggrid, TPB, 0, stream>>>(P, bias0, bias1, cf, chi, clo, flags);
    };

    // ---- layer 1 ----
    agg128_f32<<<a128g, TPB, 0, stream>>>(x_user, ptrA, colA, slab_hi, slab_lo);
    agg128_f32<<<a128g, TPB, 0, stream>>>(x_item, ptrB, colB, s2L1_hi, s2L1_lo);
    launch_gemm(slab_hi, slab_lo, wt_l1rev_h, wt_l1rev_l, 128,
                s2L1_hi, s2L1_lo, wt_l1ab_h,  wt_l1ab_l,  128,
                xi_hi,   xi_lo,   wt_r1c_h,   wt_r1c_l,   128,
                b1_rev, b1_ab, nullptr, hI_hi, hI_lo, F_PAIROUT | F_RELU);
    agg128_f32<<<a128g, TPB, 0, stream>>>(x_item, ptrC, colC, slab_hi, slab_lo);
    launch_gemm(slab_hi, slab_lo, wt_l1rrev_h, wt_l1rrev_l, 128,
                xu_hi,   xu_lo,   wt_r1rrev_h, wt_r1rrev_l, 128,
                nullptr, nullptr, nullptr, nullptr, 0,
                b1_rrev, nullptr, nullptr, hU_hi, hU_lo, F_PAIROUT | F_RELU);

    // ---- layer 2 ----
    agg256_pair<<<a256g, TPB, 0, stream>>>(hU_hi, hU_lo, ptrA, colA, slab_hi, slab_lo);
    agg256_pair<<<a256g, TPB, 0, stream>>>(hI_hi, hI_lo, ptrB, colB, s2L2_hi, s2L2_lo);
    launch_gemm(slab_hi, slab_lo, wt_l2rev_h, wt_l2rev_l, 256,
                s2L2_hi, s2L2_lo, wt_l2ab_h,  wt_l2ab_l,  256,
                hI_hi,   hI_lo,   wt_r2c_h,   wt_r2c_l,   256,
                b2_rev, b2_ab, o_item, nullptr, nullptr, 0);
    agg256_pair<<<a256g, TPB, 0, stream>>>(hI_hi, hI_lo, ptrC, colC, slab_hi, slab_lo);
    launch_gemm(slab_hi, slab_lo, wt_l2rrev_h, wt_l2rrev_l, 256,
                hU_hi,   hU_lo,   wt_r2rrev_h, wt_r2rrev_l, 256,
                nullptr, nullptr, nullptr, nullptr, 0,
                b2_rrev, nullptr, o_user, nullptr, nullptr, 0);
}

// Round 5
// 972.613 us; speedup vs baseline: 2.4016x; 1.5552x over previous
//
#include <hip/hip_runtime.h>
#include <hip/hip_bf16.h>

#define NN    100000
#define MPAD  100096          // 782*128, >= NN; pad rows zeroed/ignored
#define ER_   500000
#define EA_   500000
#define F_RELU 2

typedef __attribute__((ext_vector_type(8))) _Float16 f16x8;
typedef __attribute__((ext_vector_type(4))) float f32x4;
typedef __attribute__((address_space(3))) uint lds_uint;
typedef const __attribute__((address_space(1))) uint g_uint;

union H8 { uint4 u; _Float16 h[8]; };
union H1 { _Float16 h; ushort u; };

__device__ __forceinline__ ushort f2h(float f) { H1 c; c.h = (_Float16)f; return c.u; }

// ---------------------------------------------------------------------------
// CSR build
// ---------------------------------------------------------------------------
__global__ void count_deg(const int* __restrict__ dst, int n_edges, int* __restrict__ cnt) {
    int i = blockIdx.x * blockDim.x + threadIdx.x;
    if (i < n_edges) atomicAdd(&cnt[dst[i]], 1);
}

__global__ void fill_csr(const int* __restrict__ dst, const int* __restrict__ src, int n_edges,
                         const int* __restrict__ ptr, int* __restrict__ cur, int* __restrict__ col) {
    int i = blockIdx.x * blockDim.x + threadIdx.x;
    if (i < n_edges) {
        int d = dst[i];
        int slot = ptr[d] + atomicAdd(&cur[d], 1);
        col[slot] = src[i];
    }
}

__global__ void exscan3(const int* __restrict__ c0, int* __restrict__ p0,
                        const int* __restrict__ c1, int* __restrict__ p1,
                        const int* __restrict__ c2, int* __restrict__ p2, int n) {
    const int* cnt = (blockIdx.x == 0) ? c0 : (blockIdx.x == 1) ? c1 : c2;
    int*       ptr = (blockIdx.x == 0) ? p0 : (blockIdx.x == 1) ? p1 : p2;
    __shared__ int wsum[16];
    __shared__ int s_carry, s_tot;
    int tid = threadIdx.x, lane = tid & 63, wid = tid >> 6;
    if (tid == 0) s_carry = 0;
    __syncthreads();
    for (int base = 0; base < n; base += 4096) {
        int i0 = base + tid * 4;
        int4 v = {0, 0, 0, 0};
        if (i0 + 3 < n) v = *(const int4*)(cnt + i0);
        else {
            if (i0     < n) v.x = cnt[i0];
            if (i0 + 1 < n) v.y = cnt[i0 + 1];
            if (i0 + 2 < n) v.z = cnt[i0 + 2];
        }
        int s = v.x + v.y + v.z + v.w;
        int isc = s;
        #pragma unroll
        for (int off = 1; off < 64; off <<= 1) {
            int t = __shfl_up(isc, off, 64);
            if (lane >= off) isc += t;
        }
        if (lane == 63) wsum[wid] = isc;
        __syncthreads();
        if (wid == 0) {
            int w = (lane < 16) ? wsum[lane] : 0;
            int wsc = w;
            #pragma unroll
            for (int off = 1; off < 16; off <<= 1) {
                int t = __shfl_up(wsc, off, 64);
                if (lane >= off) wsc += t;
            }
            if (lane < 16) wsum[lane] = wsc - w;
            if (lane == 15) s_tot = wsc;
        }
        __syncthreads();
        int excl = s_carry + wsum[wid] + (isc - s);
        if (i0     < n) ptr[i0]     = excl;
        if (i0 + 1 < n) ptr[i0 + 1] = excl + v.x;
        if (i0 + 2 < n) ptr[i0 + 2] = excl + v.x + v.y;
        if (i0 + 3 < n) ptr[i0 + 3] = excl + v.x + v.y + v.z;
        __syncthreads();
        if (tid == 0) s_carry += s_tot;
        __syncthreads();
    }
    if (tid == 0) ptr[n] = s_carry;
}

// ---------------------------------------------------------------------------
// Weight prep: W[K][256] fp32 (+opt addend) -> transposed fp16 Wt[256][K]
// ---------------------------------------------------------------------------
__global__ void wprep(const float* __restrict__ W0, const float* __restrict__ W1, int K,
                      ushort* __restrict__ T) {
    int i = blockIdx.x * blockDim.x + threadIdx.x;
    if (i >= K * 256) return;
    int k = i >> 8, n = i & 255;
    float v = W0[i];
    if (W1) v += W1[i];
    T[n * K + k] = f2h(v);
}

// fp32 [nvalid] -> fp16 [ntotal]; pad zeroed. 8 elems/thread.
__global__ void cvt_x(const float* __restrict__ x, ushort* __restrict__ o,
                      long nvalid, long ntotal) {
    long i = ((long)blockIdx.x * blockDim.x + threadIdx.x) * 8;
    if (i >= ntotal) return;
    float4 v0 = {0.f,0.f,0.f,0.f}, v1 = {0.f,0.f,0.f,0.f};
    if (i < nvalid) { v0 = *(const float4*)(x + i); v1 = *(const float4*)(x + i + 4); }
    H8 r;
    r.h[0]=(_Float16)v0.x; r.h[1]=(_Float16)v0.y; r.h[2]=(_Float16)v0.z; r.h[3]=(_Float16)v0.w;
    r.h[4]=(_Float16)v1.x; r.h[5]=(_Float16)v1.y; r.h[6]=(_Float16)v1.z; r.h[7]=(_Float16)v1.w;
    *(uint4*)(o + i) = r.u;
}

// ---------------------------------------------------------------------------
// Aggregations: mean over CSR neighbors of fp16 rows -> fp16 rows, pads zeroed
// D=128: 16 lanes/node (16B each). D=256: 32 lanes/node.
// ---------------------------------------------------------------------------
__global__ void agg128_h(const ushort* __restrict__ x, const int* __restrict__ ptr,
                         const int* __restrict__ col, ushort* __restrict__ out) {
    int g = blockIdx.x * blockDim.x + threadIdx.x;
    int node = g >> 4, l = g & 15;
    if (node >= MPAD) return;
    size_t ob = (size_t)node * 128 + l * 8;
    if (node >= NN) { *(uint4*)(out + ob) = make_uint4(0,0,0,0); return; }
    int p0 = ptr[node], p1 = ptr[node + 1];
    float a[8] = {0.f,0.f,0.f,0.f,0.f,0.f,0.f,0.f};
    for (int e = p0; e < p1; ++e) {
        H8 v; v.u = *(const uint4*)(x + (size_t)col[e] * 128 + l * 8);
        #pragma unroll
        for (int k = 0; k < 8; k++) a[k] += (float)v.h[k];
    }
    float inv = (p1 > p0) ? 1.0f / (float)(p1 - p0) : 0.0f;
    H8 r;
    #pragma unroll
    for (int k = 0; k < 8; k++) r.h[k] = (_Float16)(a[k] * inv);
    *(uint4*)(out + ob) = r.u;
}

__global__ void agg256_h(const ushort* __restrict__ x, const int* __restrict__ ptr,
                         const int* __restrict__ col, ushort* __restrict__ out) {
    int g = blockIdx.x * blockDim.x + threadIdx.x;
    int node = g >> 5, l = g & 31;
    if (node >= MPAD) return;
    size_t ob = (size_t)node * 256 + l * 8;
    if (node >= NN) { *(uint4*)(out + ob) = make_uint4(0,0,0,0); return; }
    int p0 = ptr[node], p1 = ptr[node + 1];
    float a[8] = {0.f,0.f,0.f,0.f,0.f,0.f,0.f,0.f};
    for (int e = p0; e < p1; ++e) {
        H8 v; v.u = *(const uint4*)(x + (size_t)col[e] * 256 + l * 8);
        #pragma unroll
        for (int k = 0; k < 8; k++) a[k] += (float)v.h[k];
    }
    float inv = (p1 > p0) ? 1.0f / (float)(p1 - p0) : 0.0f;
    H8 r;
    #pragma unroll
    for (int k = 0; k < 8; k++) r.h[k] = (_Float16)(a[k] * inv);
    *(uint4*)(out + ob) = r.u;
}

// ---------------------------------------------------------------------------
// fp16 MFMA GEMM, up to 3 fused parts (m97 structure).
// C[MPAD,256] = sum_p A_p[M,Kp] @ W_p[Kp,256]  (+bias) (relu)
// A planes [MPAD][K] fp16; W planes transposed [256][K] fp16.
// Block 256 thr / 4 waves (2x2); tile 128(M) x 128(N); BK=64.
// Both operands staged via global_load_lds w16, linear LDS dest,
// inverse-swizzled source chunk (q = s ^ (row&7)), swizzled ds_read.
// ---------------------------------------------------------------------------
struct GP {
    const ushort *A0, *W0, *A1, *W1, *A2, *W2;
    int ksh0, ksh1, ksh2;   // log2(K) per part
    int c1, c2, S;          // cumulative BK=64 step bounds
};

__global__ __launch_bounds__(256)
void gemm_f16(GP P, const float* __restrict__ b0, const float* __restrict__ b1,
              float* __restrict__ Cf, ushort* __restrict__ Ch, int flags) {
    __shared__ ushort sA[128 * 64];   // [row][k] fp16, chunk-swizzled
    __shared__ ushort sW[128 * 64];   // [ncol][k]
    const int tid = threadIdx.x;
    const int m0 = blockIdx.x * 128, n0 = blockIdx.y * 128;
    const int lane = tid & 63, w = tid >> 6;
    const int wr = (w >> 1) * 64, wc = (w & 1) * 64;   // wave origin in tile
    const int fcol = lane & 15, fq = lane >> 4;        // frag index / k-quarter
    const int srow = tid >> 3, sc = tid & 7;           // staging row-in-32 / slot

    f32x4 acc[4][4];
    #pragma unroll
    for (int i = 0; i < 4; i++)
        #pragma unroll
        for (int j = 0; j < 4; j++) acc[i][j] = (f32x4){0.f,0.f,0.f,0.f};

    #pragma unroll 1
    for (int t = 0; t < P.S; ++t) {
        // resolve part (t uniform)
        int p = (t >= P.c1) + (t >= P.c2);
        const ushort* A = (p == 2) ? P.A2 : (p == 1) ? P.A1 : P.A0;
        const ushort* W = (p == 2) ? P.W2 : (p == 1) ? P.W1 : P.W0;
        int ksh = (p == 2) ? P.ksh2 : (p == 1) ? P.ksh1 : P.ksh0;
        int base = (p == 2) ? P.c2 : (p == 1) ? P.c1 : 0;
        int k0 = (t - base) << 6;

        // stage A & W tiles: 4 issues each (32 rows x 128B per issue)
        #pragma unroll
        for (int ii = 0; ii < 4; ++ii) {
            int row = ii * 32 + srow;
            int q = sc ^ (row & 7);
            const ushort* srcA = A + (((size_t)(m0 + row)) << ksh) + k0 + q * 8;
            const ushort* srcW = W + (((size_t)(n0 + row)) << ksh) + k0 + q * 8;
            __builtin_amdgcn_global_load_lds((g_uint*)srcA,
                (lds_uint*)(sA + row * 64 + sc * 8), 16, 0, 0);
            __builtin_amdgcn_global_load_lds((g_uint*)srcW,
                (lds_uint*)(sW + row * 64 + sc * 8), 16, 0, 0);
        }
        __syncthreads();   // drain staging

        #pragma unroll
        for (int kk = 0; kk < 2; ++kk) {
            f16x8 a[4], b[4];
            #pragma unroll
            for (int i = 0; i < 4; ++i) {
                int ra = wr + i * 16 + fcol;
                int s = (fq + kk * 4) ^ (ra & 7);
                a[i] = *(const f16x8*)(sA + ra * 64 + s * 8);
            }
            #pragma unroll
            for (int j = 0; j < 4; ++j) {
                int rw = wc + j * 16 + fcol;
                int s = (fq + kk * 4) ^ (rw & 7);
                b[j] = *(const f16x8*)(sW + rw * 64 + s * 8);
            }
            #pragma unroll
            for (int i = 0; i < 4; ++i)
                #pragma unroll
                for (int j = 0; j < 4; ++j)
                    acc[i][j] = __builtin_amdgcn_mfma_f32_16x16x32_f16(a[i], b[j], acc[i][j], 0, 0, 0);
        }
        __syncthreads();   // protect buffer reuse
    }

    const bool relu = flags & F_RELU;
    float bb[4];
    #pragma unroll
    for (int j = 0; j < 4; ++j) {
        int cg = n0 + wc + j * 16 + fcol;
        float v = 0.f;
        if (b0) v += b0[cg];
        if (b1) v += b1[cg];
        bb[j] = v;
    }
    #pragma unroll
    for (int i = 0; i < 4; ++i) {
        #pragma unroll
        for (int r = 0; r < 4; ++r) {
            int gm = m0 + wr + i * 16 + fq * 4 + r;
            if (gm >= NN) continue;
            size_t rowb = (size_t)gm * 256;
            #pragma unroll
            for (int j = 0; j < 4; ++j) {
                size_t idx = rowb + n0 + wc + j * 16 + fcol;
                float v = acc[i][j][r] + bb[j];
                if (relu) v = fmaxf(v, 0.f);
                if (Ch) Ch[idx] = f2h(v);
                else    Cf[idx] = v;
            }
        }
    }
}

// ---------------------------------------------------------------------------
extern "C" void kernel_launch(void* const* d_in, const int* in_sizes, int n_in,
                              void* d_out, int out_size, void* d_ws, size_t ws_size,
                              hipStream_t stream) {
    const float* x_user = (const float*)d_in[0];
    const float* x_item = (const float*)d_in[1];
    const int* src_rev  = (const int*)d_in[2];
    const int* dst_rev  = (const int*)d_in[3];
    const int* src_ab   = (const int*)d_in[4];
    const int* dst_ab   = (const int*)d_in[5];
    const float* Wl1_rev  = (const float*)d_in[6];
    const float* Wr1_rev  = (const float*)d_in[7];
    const float* b1_rev   = (const float*)d_in[8];
    const float* Wl1_rrev = (const float*)d_in[9];
    const float* Wr1_rrev = (const float*)d_in[10];
    const float* b1_rrev  = (const float*)d_in[11];
    const float* Wl1_ab   = (const float*)d_in[12];
    const float* Wr1_ab   = (const float*)d_in[13];
    const float* b1_ab    = (const float*)d_in[14];
    const float* Wl2_rev  = (const float*)d_in[15];
    const float* Wr2_rev  = (const float*)d_in[16];
    const float* b2_rev   = (const float*)d_in[17];
    const float* Wl2_rrev = (const float*)d_in[18];
    const float* Wr2_rrev = (const float*)d_in[19];
    const float* b2_rrev  = (const float*)d_in[20];
    const float* Wl2_ab   = (const float*)d_in[21];
    const float* Wr2_ab   = (const float*)d_in[22];
    const float* b2_ab    = (const float*)d_in[23];

    float* o_user = (float*)d_out;
    float* o_item = (float*)d_out + (size_t)NN * 256;

    char* ws = (char*)d_ws;
    size_t off = 0;
    auto alloc = [&](size_t bytes) -> void* {
        void* p = ws + off;
        off += (bytes + 255) & ~(size_t)255;
        return p;
    };
    const size_t P256 = (size_t)MPAD * 256 * 2;   // fp16 plane bytes, 256 wide
    const size_t P128 = (size_t)MPAD * 128 * 2;
    ushort* xu     = (ushort*)alloc(P128);
    ushort* xi     = (ushort*)alloc(P128);
    ushort* slabA  = (ushort*)alloc(P128);
    ushort* slabB  = (ushort*)alloc(P128);
    ushort* hI     = (ushort*)alloc(P256);
    ushort* hU     = (ushort*)alloc(P256);
    ushort* slab2A = (ushort*)alloc(P256);
    ushort* slab2B = (ushort*)alloc(P256);
    const size_t W1SZ = 128 * 256 * 2, W2SZ = 256 * 256 * 2;
    ushort* wt_l1rev  = (ushort*)alloc(W1SZ);
    ushort* wt_l1ab   = (ushort*)alloc(W1SZ);
    ushort* wt_l1rrev = (ushort*)alloc(W1SZ);
    ushort* wt_r1c    = (ushort*)alloc(W1SZ);
    ushort* wt_r1rrev = (ushort*)alloc(W1SZ);
    ushort* wt_l2rev  = (ushort*)alloc(W2SZ);
    ushort* wt_l2ab   = (ushort*)alloc(W2SZ);
    ushort* wt_l2rrev = (ushort*)alloc(W2SZ);
    ushort* wt_r2c    = (ushort*)alloc(W2SZ);
    ushort* wt_r2rrev = (ushort*)alloc(W2SZ);
    int* ptrA = (int*)alloc((NN + 1) * 4);
    int* ptrB = (int*)alloc((NN + 1) * 4);
    int* ptrC = (int*)alloc((NN + 1) * 4);
    int* colA = (int*)alloc((size_t)ER_ * 4);
    int* colB = (int*)alloc((size_t)EA_ * 4);
    int* colC = (int*)alloc((size_t)ER_ * 4);
    int* curA = (int*)alloc((size_t)3 * NN * 4);
    int* curB = curA + NN;
    int* curC = curA + 2 * NN;

    const int TPB = 256;
    dim3 egrid((ER_ + TPB - 1) / TPB);

    // CSR build
    hipMemsetAsync(curA, 0, (size_t)3 * NN * 4, stream);
    count_deg<<<egrid, TPB, 0, stream>>>(dst_rev, ER_, curA);
    count_deg<<<egrid, TPB, 0, stream>>>(dst_ab,  EA_, curB);
    count_deg<<<egrid, TPB, 0, stream>>>(src_rev, ER_, curC);
    exscan3<<<3, 1024, 0, stream>>>(curA, ptrA, curB, ptrB, curC, ptrC, NN);
    hipMemsetAsync(curA, 0, (size_t)3 * NN * 4, stream);
    fill_csr<<<egrid, TPB, 0, stream>>>(dst_rev, src_rev, ER_, ptrA, curA, colA);
    fill_csr<<<egrid, TPB, 0, stream>>>(dst_ab,  src_ab,  EA_, ptrB, curB, colB);
    fill_csr<<<egrid, TPB, 0, stream>>>(src_rev, dst_rev, ER_, ptrC, curC, colC);

    // weight prep (transpose + fp16)
    dim3 wg1((128 * 256 + TPB - 1) / TPB), wg2((256 * 256 + TPB - 1) / TPB);
    wprep<<<wg1, TPB, 0, stream>>>(Wl1_rev,  nullptr, 128, wt_l1rev);
    wprep<<<wg1, TPB, 0, stream>>>(Wl1_ab,   nullptr, 128, wt_l1ab);
    wprep<<<wg1, TPB, 0, stream>>>(Wl1_rrev, nullptr, 128, wt_l1rrev);
    wprep<<<wg1, TPB, 0, stream>>>(Wr1_rev,  Wr1_ab,  128, wt_r1c);
    wprep<<<wg1, TPB, 0, stream>>>(Wr1_rrev, nullptr, 128, wt_r1rrev);
    wprep<<<wg2, TPB, 0, stream>>>(Wl2_rev,  nullptr, 256, wt_l2rev);
    wprep<<<wg2, TPB, 0, stream>>>(Wl2_ab,   nullptr, 256, wt_l2ab);
    wprep<<<wg2, TPB, 0, stream>>>(Wl2_rrev, nullptr, 256, wt_l2rrev);
    wprep<<<wg2, TPB, 0, stream>>>(Wr2_rev,  Wr2_ab,  256, wt_r2c);
    wprep<<<wg2, TPB, 0, stream>>>(Wr2_rrev, nullptr, 256, wt_r2rrev);

    // x -> fp16 planes
    long n128v = (long)NN * 128, n128t = (long)MPAD * 128;
    dim3 cxg(n128t / 8 / TPB);
    cvt_x<<<cxg, TPB, 0, stream>>>(x_user, xu, n128v, n128t);
    cvt_x<<<cxg, TPB, 0, stream>>>(x_item, xi, n128v, n128t);

    dim3 a128g((size_t)MPAD * 16 / TPB), a256g((size_t)MPAD * 32 / TPB);
    dim3 ggrid(MPAD / 128, 2);

    auto launch_gemm = [&](const ushort* a0, const ushort* w0, int K0,
                           const ushort* a1, const ushort* w1, int K1,
                           const ushort* a2, const ushort* w2, int K2,
                           const float* bias0, const float* bias1,
                           float* cf, ushort* ch, int flags) {
        GP P;
        P.A0 = a0; P.W0 = w0;
        P.A1 = a1 ? a1 : a0; P.W1 = w1 ? w1 : w0;
        P.A2 = a2 ? a2 : a0; P.W2 = w2 ? w2 : w0;
        P.ksh0 = (K0 == 256) ? 8 : 7;
        P.ksh1 = (K1 == 256) ? 8 : 7;
        P.ksh2 = (K2 == 256) ? 8 : 7;
        P.c1 = K0 >> 6; P.c2 = P.c1 + (K1 >> 6); P.S = P.c2 + (K2 >> 6);
        gemm_f16<<<ggrid, TPB, 0, stream>>>(P, bias0, bias1, cf, ch, flags);
    };

    // ---- layer 1 ----
    agg128_h<<<a128g, TPB, 0, stream>>>(xu, ptrA, colA, slabA);
    agg128_h<<<a128g, TPB, 0, stream>>>(xi, ptrB, colB, slabB);
    launch_gemm(slabA, wt_l1rev, 128, slabB, wt_l1ab, 128, xi, wt_r1c, 128,
                b1_rev, b1_ab, nullptr, hI, F_RELU);
    agg128_h<<<a128g, TPB, 0, stream>>>(xi, ptrC, colC, slabA);
    launch_gemm(slabA, wt_l1rrev, 128, xu, wt_r1rrev, 128, nullptr, nullptr, 0,
                b1_rrev, nullptr, nullptr, hU, F_RELU);

    // ---- layer 2 ----
    agg256_h<<<a256g, TPB, 0, stream>>>(hU, ptrA, colA, slab2A);
    agg256_h<<<a256g, TPB, 0, stream>>>(hI, ptrB, colB, slab2B);
    launch_gemm(slab2A, wt_l2rev, 256, slab2B, wt_l2ab, 256, hI, wt_r2c, 256,
                b2_rev, b2_ab, o_item, nullptr, 0);
    agg256_h<<<a256g, TPB, 0, stream>>>(hI, ptrC, colC, slab2A);
    launch_gemm(slab2A, wt_l2rrev, 256, hU, wt_r2rrev, 256, nullptr, nullptr, 0,
                b2_rrev, nullptr, o_user, nullptr, 0);
}

// Round 7
// 856.456 us; speedup vs baseline: 2.7273x; 1.1356x over previous
//
#include <hip/hip_runtime.h>
#include <hip/hip_bf16.h>

#define NN    100000
#define MPAD  100096          // 782*128, >= NN; pad rows zeroed/ignored
#define ER_   500000
#define EA_   500000
#define NCH   25              // scan chunks of 4096 (25*4096 >= NN)
#define F_RELU 2

typedef __attribute__((ext_vector_type(8))) _Float16 f16x8;
typedef __attribute__((ext_vector_type(4))) float f32x4;
typedef __attribute__((address_space(3))) uint lds_uint;
typedef const __attribute__((address_space(1))) uint g_uint;

union H8 { uint4 u; _Float16 h[8]; };
union H1 { _Float16 h; ushort u; };

__device__ __forceinline__ ushort f2h(float f) { H1 c; c.h = (_Float16)f; return c.u; }

// ---------------------------------------------------------------------------
// CSR build: fused count / fill, parallel 3-kernel exclusive scan
// ---------------------------------------------------------------------------
__global__ void count3(const int* __restrict__ dst_rev, const int* __restrict__ dst_ab,
                       const int* __restrict__ src_rev, int* __restrict__ cnt /*3*NN*/) {
    int i = blockIdx.x * blockDim.x + threadIdx.x;
    if (i < ER_)                 atomicAdd(&cnt[dst_rev[i]], 1);
    else if (i < ER_ + EA_)      atomicAdd(&cnt[NN + dst_ab[i - ER_]], 1);
    else if (i < ER_ + EA_ + ER_) atomicAdd(&cnt[2 * NN + src_rev[i - ER_ - EA_]], 1);
}

__global__ void fill3(const int* __restrict__ dst_rev, const int* __restrict__ src_rev,
                      const int* __restrict__ dst_ab, const int* __restrict__ src_ab,
                      const int* __restrict__ pA, const int* __restrict__ pB,
                      const int* __restrict__ pC, int* __restrict__ cur /*3*NN*/,
                      int* __restrict__ colA, int* __restrict__ colB, int* __restrict__ colC) {
    int i = blockIdx.x * blockDim.x + threadIdx.x;
    if (i < ER_) {
        int d = dst_rev[i];
        colA[pA[d] + atomicAdd(&cur[d], 1)] = src_rev[i];
    } else if (i < ER_ + EA_) {
        int e = i - ER_, d = dst_ab[e];
        colB[pB[d] + atomicAdd(&cur[NN + d], 1)] = src_ab[e];
    } else if (i < ER_ + EA_ + ER_) {
        int e = i - ER_ - EA_, d = src_rev[e];
        colC[pC[d] + atomicAdd(&cur[2 * NN + d], 1)] = dst_rev[e];
    }
}

// per-chunk sums: grid 3*NCH blocks
__global__ void scan_part(const int* __restrict__ cnt /*3*NN*/, int* __restrict__ part) {
    int b = blockIdx.x, a = b / NCH, c = b % NCH;
    const int* src = cnt + a * NN;
    int base = c * 4096 + threadIdx.x * 16;
    int s = 0;
    #pragma unroll
    for (int k = 0; k < 16; k += 4) {
        int i = base + k;
        if (i + 3 < NN) { int4 v = *(const int4*)(src + i); s += v.x + v.y + v.z + v.w; }
        else { for (int j = 0; j < 4; j++) if (i + j < NN) s += src[i + j]; }
    }
    __shared__ int ws[4];
    int lane = threadIdx.x & 63, wid = threadIdx.x >> 6;
    #pragma unroll
    for (int o = 32; o > 0; o >>= 1) s += __shfl_down(s, o, 64);
    if (lane == 0) ws[wid] = s;
    __syncthreads();
    if (threadIdx.x == 0) part[b] = ws[0] + ws[1] + ws[2] + ws[3];
}

// chunk offsets + totals: 1 block
__global__ void scan_off(const int* __restrict__ part, int* __restrict__ choff,
                         int* __restrict__ pA, int* __restrict__ pB, int* __restrict__ pC) {
    int a = threadIdx.x;
    if (a < 3) {
        int acc = 0;
        for (int c = 0; c < NCH; c++) { choff[a * NCH + c] = acc; acc += part[a * NCH + c]; }
        int* p = (a == 0) ? pA : (a == 1) ? pB : pC;
        p[NN] = acc;
    }
}

// apply: grid 3*NCH blocks; exclusive scan within chunk + chunk offset
__global__ void scan_apply(const int* __restrict__ cnt, const int* __restrict__ choff,
                           int* __restrict__ pA, int* __restrict__ pB, int* __restrict__ pC) {
    int b = blockIdx.x, a = b / NCH, c = b % NCH;
    const int* src = cnt + a * NN;
    int* ptr = (a == 0) ? pA : (a == 1) ? pB : pC;
    int tid = threadIdx.x, lane = tid & 63, wid = tid >> 6;
    int base = c * 4096 + tid * 16;
    int v[16], s = 0;
    #pragma unroll
    for (int k = 0; k < 16; k++) { int i = base + k; v[k] = (i < NN) ? src[i] : 0; s += v[k]; }
    int isc = s;
    #pragma unroll
    for (int o = 1; o < 64; o <<= 1) { int t = __shfl_up(isc, o, 64); if (lane >= o) isc += t; }
    __shared__ int wsum[4];
    if (lane == 63) wsum[wid] = isc;
    __syncthreads();
    int woff = 0;
    for (int wj = 0; wj < wid; wj++) woff += wsum[wj];
    int excl = choff[a * NCH + c] + woff + (isc - s);
    #pragma unroll
    for (int k = 0; k < 16; k++) { int i = base + k; if (i < NN) ptr[i] = excl; excl += v[k]; }
}

// ---------------------------------------------------------------------------
// Fused prep: cvt x_user/x_item fp32->fp16 planes + 10 weight transposes
// ---------------------------------------------------------------------------
struct PrepArgs {
    const float* xsrc[2]; ushort* xdst[2];
    const float* W0[10]; const float* W1[10]; ushort* T[10];
};

__global__ void prep_all(PrepArgs A) {
    const long CVB = (long)MPAD * 128 / 8 / 256;   // 6256 blocks per cvt
    long b = blockIdx.x;
    if (b < 2 * CVB) {
        int which = (b >= CVB);
        long lb = b - which * CVB;
        long i = (lb * 256 + threadIdx.x) * 8;
        const float* x = A.xsrc[which];
        ushort* o = A.xdst[which];
        float4 v0 = {0.f,0.f,0.f,0.f}, v1 = {0.f,0.f,0.f,0.f};
        if (i < (long)NN * 128) { v0 = *(const float4*)(x + i); v1 = *(const float4*)(x + i + 4); }
        H8 r;
        r.h[0]=(_Float16)v0.x; r.h[1]=(_Float16)v0.y; r.h[2]=(_Float16)v0.z; r.h[3]=(_Float16)v0.w;
        r.h[4]=(_Float16)v1.x; r.h[5]=(_Float16)v1.y; r.h[6]=(_Float16)v1.z; r.h[7]=(_Float16)v1.w;
        *(uint4*)(o + i) = r.u;
        return;
    }
    long j = (b - 2 * CVB) * 256 + threadIdx.x;    // 0 .. 491519
    int idx, rem, K;
    if (j < 5 * 32768) { idx = j >> 15; rem = j & 32767; K = 128; }
    else {
        long j2 = j - 5 * 32768;
        if (j2 >= 5L * 65536) return;
        idx = 5 + (int)(j2 >> 16); rem = (int)(j2 & 65535); K = 256;
    }
    int k = rem >> 8, n = rem & 255;
    float v = A.W0[idx][rem];
    if (A.W1[idx]) v += A.W1[idx][rem];
    A.T[idx][n * K + k] = f2h(v);
}

// ---------------------------------------------------------------------------
// Fused aggregations: 3 directions in one dispatch. Mean of fp16 rows, pad->0
// ---------------------------------------------------------------------------
__global__ void agg3_128(const ushort* __restrict__ xu, const ushort* __restrict__ xi,
                         const int* __restrict__ pA, const int* __restrict__ cA,
                         const int* __restrict__ pB, const int* __restrict__ cB,
                         const int* __restrict__ pC, const int* __restrict__ cC,
                         ushort* __restrict__ sA, ushort* __restrict__ sB,
                         ushort* __restrict__ sC) {
    const int SEG = MPAD * 16 / 256;   // 6256
    int seg = blockIdx.x / SEG, lb = blockIdx.x % SEG;
    const ushort* x; const int* ptr; const int* col; ushort* out;
    if (seg == 0)      { x = xu; ptr = pA; col = cA; out = sA; }
    else if (seg == 1) { x = xi; ptr = pB; col = cB; out = sB; }
    else               { x = xi; ptr = pC; col = cC; out = sC; }
    int g = lb * 256 + threadIdx.x;
    int node = g >> 4, l = g & 15;
    if (node >= MPAD) return;
    size_t ob = (size_t)node * 128 + l * 8;
    if (node >= NN) { *(uint4*)(out + ob) = make_uint4(0,0,0,0); return; }
    int p0 = ptr[node], p1 = ptr[node + 1];
    float a[8] = {0.f,0.f,0.f,0.f,0.f,0.f,0.f,0.f};
    for (int e = p0; e < p1; ++e) {
        H8 v; v.u = *(const uint4*)(x + (size_t)col[e] * 128 + l * 8);
        #pragma unroll
        for (int k = 0; k < 8; k++) a[k] += (float)v.h[k];
    }
    float inv = (p1 > p0) ? 1.0f / (float)(p1 - p0) : 0.0f;
    H8 r;
    #pragma unroll
    for (int k = 0; k < 8; k++) r.h[k] = (_Float16)(a[k] * inv);
    *(uint4*)(out + ob) = r.u;
}

__global__ void agg3_256(const ushort* __restrict__ hU, const ushort* __restrict__ hI,
                         const int* __restrict__ pA, const int* __restrict__ cA,
                         const int* __restrict__ pB, const int* __restrict__ cB,
                         const int* __restrict__ pC, const int* __restrict__ cC,
                         ushort* __restrict__ sA, ushort* __restrict__ sB,
                         ushort* __restrict__ sC) {
    const int SEG = MPAD * 32 / 256;   // 12512
    int seg = blockIdx.x / SEG, lb = blockIdx.x % SEG;
    const ushort* x; const int* ptr; const int* col; ushort* out;
    if (seg == 0)      { x = hU; ptr = pA; col = cA; out = sA; }
    else if (seg == 1) { x = hI; ptr = pB; col = cB; out = sB; }
    else               { x = hI; ptr = pC; col = cC; out = sC; }
    int g = lb * 256 + threadIdx.x;
    int node = g >> 5, l = g & 31;
    if (node >= MPAD) return;
    size_t ob = (size_t)node * 256 + l * 8;
    if (node >= NN) { *(uint4*)(out + ob) = make_uint4(0,0,0,0); return; }
    int p0 = ptr[node], p1 = ptr[node + 1];
    float a[8] = {0.f,0.f,0.f,0.f,0.f,0.f,0.f,0.f};
    for (int e = p0; e < p1; ++e) {
        H8 v; v.u = *(const uint4*)(x + (size_t)col[e] * 256 + l * 8);
        #pragma unroll
        for (int k = 0; k < 8; k++) a[k] += (float)v.h[k];
    }
    float inv = (p1 > p0) ? 1.0f / (float)(p1 - p0) : 0.0f;
    H8 r;
    #pragma unroll
    for (int k = 0; k < 8; k++) r.h[k] = (_Float16)(a[k] * inv);
    *(uint4*)(out + ob) = r.u;
}

// ---------------------------------------------------------------------------
// fp16 MFMA GEMM, up to 3 fused parts, two independent problems per dispatch
// (blockIdx.z selects). Body identical to round-5 verified gemm_f16.
// ---------------------------------------------------------------------------
struct GP {
    const ushort *A0, *W0, *A1, *W1, *A2, *W2;
    int ksh0, ksh1, ksh2;
    int c1, c2, S;
};

__global__ __launch_bounds__(256)
void gemm2x(GP Pa, const float* b0a, const float* b1a, float* Cfa, ushort* Cha, int fla,
            GP Pb, const float* b0b, const float* b1b, float* Cfb, ushort* Chb, int flb) {
    GP P; const float *b0, *b1; float* Cf; ushort* Ch; int flags;
    if (blockIdx.z == 0) { P = Pa; b0 = b0a; b1 = b1a; Cf = Cfa; Ch = Cha; flags = fla; }
    else                 { P = Pb; b0 = b0b; b1 = b1b; Cf = Cfb; Ch = Chb; flags = flb; }

    __shared__ ushort sA[128 * 64];
    __shared__ ushort sW[128 * 64];
    const int tid = threadIdx.x;
    const int m0 = blockIdx.x * 128, n0 = blockIdx.y * 128;
    const int lane = tid & 63, w = tid >> 6;
    const int wr = (w >> 1) * 64, wc = (w & 1) * 64;
    const int fcol = lane & 15, fq = lane >> 4;
    const int srow = tid >> 3, sc = tid & 7;

    f32x4 acc[4][4];
    #pragma unroll
    for (int i = 0; i < 4; i++)
        #pragma unroll
        for (int j = 0; j < 4; j++) acc[i][j] = (f32x4){0.f,0.f,0.f,0.f};

    #pragma unroll 1
    for (int t = 0; t < P.S; ++t) {
        int p = (t >= P.c1) + (t >= P.c2);
        const ushort* A = (p == 2) ? P.A2 : (p == 1) ? P.A1 : P.A0;
        const ushort* W = (p == 2) ? P.W2 : (p == 1) ? P.W1 : P.W0;
        int ksh  = (p == 2) ? P.ksh2 : (p == 1) ? P.ksh1 : P.ksh0;
        int base = (p == 2) ? P.c2 : (p == 1) ? P.c1 : 0;
        int k0 = (t - base) << 6;

        #pragma unroll
        for (int ii = 0; ii < 4; ++ii) {
            int row = ii * 32 + srow;
            int q = sc ^ (row & 7);
            const ushort* srcA = A + (((size_t)(m0 + row)) << ksh) + k0 + q * 8;
            const ushort* srcW = W + (((size_t)(n0 + row)) << ksh) + k0 + q * 8;
            __builtin_amdgcn_global_load_lds((g_uint*)srcA,
                (lds_uint*)(sA + row * 64 + sc * 8), 16, 0, 0);
            __builtin_amdgcn_global_load_lds((g_uint*)srcW,
                (lds_uint*)(sW + row * 64 + sc * 8), 16, 0, 0);
        }
        __syncthreads();

        #pragma unroll
        for (int kk = 0; kk < 2; ++kk) {
            f16x8 a[4], b[4];
            #pragma unroll
            for (int i = 0; i < 4; ++i) {
                int ra = wr + i * 16 + fcol;
                int s = (fq + kk * 4) ^ (ra & 7);
                a[i] = *(const f16x8*)(sA + ra * 64 + s * 8);
            }
            #pragma unroll
            for (int j = 0; j < 4; ++j) {
                int rw = wc + j * 16 + fcol;
                int s = (fq + kk * 4) ^ (rw & 7);
                b[j] = *(const f16x8*)(sW + rw * 64 + s * 8);
            }
            #pragma unroll
            for (int i = 0; i < 4; ++i)
                #pragma unroll
                for (int j = 0; j < 4; ++j)
                    acc[i][j] = __builtin_amdgcn_mfma_f32_16x16x32_f16(a[i], b[j], acc[i][j], 0, 0, 0);
        }
        __syncthreads();
    }

    const bool relu = flags & F_RELU;
    float bb[4];
    #pragma unroll
    for (int j = 0; j < 4; ++j) {
        int cg = n0 + wc + j * 16 + fcol;
        float v = 0.f;
        if (b0) v += b0[cg];
        if (b1) v += b1[cg];
        bb[j] = v;
    }
    #pragma unroll
    for (int i = 0; i < 4; ++i) {
        #pragma unroll
        for (int r = 0; r < 4; ++r) {
            int gm = m0 + wr + i * 16 + fq * 4 + r;
            if (gm >= NN) continue;
            size_t rowb = (size_t)gm * 256;
            #pragma unroll
            for (int j = 0; j < 4; ++j) {
                size_t idx = rowb + n0 + wc + j * 16 + fcol;
                float v = acc[i][j][r] + bb[j];
                if (relu) v = fmaxf(v, 0.f);
                if (Ch) Ch[idx] = f2h(v);
                else    Cf[idx] = v;
            }
        }
    }
}

// ---------------------------------------------------------------------------
extern "C" void kernel_launch(void* const* d_in, const int* in_sizes, int n_in,
                              void* d_out, int out_size, void* d_ws, size_t ws_size,
                              hipStream_t stream) {
    const float* x_user = (const float*)d_in[0];
    const float* x_item = (const float*)d_in[1];
    const int* src_rev  = (const int*)d_in[2];
    const int* dst_rev  = (const int*)d_in[3];
    const int* src_ab   = (const int*)d_in[4];
    const int* dst_ab   = (const int*)d_in[5];
    const float* Wl1_rev  = (const float*)d_in[6];
    const float* Wr1_rev  = (const float*)d_in[7];
    const float* b1_rev   = (const float*)d_in[8];
    const float* Wl1_rrev = (const float*)d_in[9];
    const float* Wr1_rrev = (const float*)d_in[10];
    const float* b1_rrev  = (const float*)d_in[11];
    const float* Wl1_ab   = (const float*)d_in[12];
    const float* Wr1_ab   = (const float*)d_in[13];
    const float* b1_ab    = (const float*)d_in[14];
    const float* Wl2_rev  = (const float*)d_in[15];
    const float* Wr2_rev  = (const float*)d_in[16];
    const float* b2_rev   = (const float*)d_in[17];
    const float* Wl2_rrev = (const float*)d_in[18];
    const float* Wr2_rrev = (const float*)d_in[19];
    const float* b2_rrev  = (const float*)d_in[20];
    const float* Wl2_ab   = (const float*)d_in[21];
    const float* Wr2_ab   = (const float*)d_in[22];
    const float* b2_ab    = (const float*)d_in[23];

    float* o_user = (float*)d_out;
    float* o_item = (float*)d_out + (size_t)NN * 256;

    char* ws = (char*)d_ws;
    size_t off = 0;
    auto alloc = [&](size_t bytes) -> void* {
        void* p = ws + off;
        off += (bytes + 255) & ~(size_t)255;
        return p;
    };
    const size_t P256 = (size_t)MPAD * 256 * 2;
    const size_t P128 = (size_t)MPAD * 128 * 2;
    ushort* xu     = (ushort*)alloc(P128);
    ushort* xi     = (ushort*)alloc(P128);
    ushort* slabA  = (ushort*)alloc(P128);
    ushort* slabB  = (ushort*)alloc(P128);
    ushort* slabC  = (ushort*)alloc(P128);
    ushort* hI     = (ushort*)alloc(P256);
    ushort* hU     = (ushort*)alloc(P256);
    ushort* s2A    = (ushort*)alloc(P256);
    ushort* s2B    = (ushort*)alloc(P256);
    ushort* s2C    = (ushort*)alloc(P256);
    const size_t W1SZ = 128 * 256 * 2, W2SZ = 256 * 256 * 2;
    ushort* wt_l1rev  = (ushort*)alloc(W1SZ);
    ushort* wt_l1ab   = (ushort*)alloc(W1SZ);
    ushort* wt_l1rrev = (ushort*)alloc(W1SZ);
    ushort* wt_r1c    = (ushort*)alloc(W1SZ);
    ushort* wt_r1rrev = (ushort*)alloc(W1SZ);
    ushort* wt_l2rev  = (ushort*)alloc(W2SZ);
    ushort* wt_l2ab   = (ushort*)alloc(W2SZ);
    ushort* wt_l2rrev = (ushort*)alloc(W2SZ);
    ushort* wt_r2c    = (ushort*)alloc(W2SZ);
    ushort* wt_r2rrev = (ushort*)alloc(W2SZ);
    int* ptrA = (int*)alloc((NN + 1) * 4);
    int* ptrB = (int*)alloc((NN + 1) * 4);
    int* ptrC = (int*)alloc((NN + 1) * 4);
    int* colA = (int*)alloc((size_t)ER_ * 4);
    int* colB = (int*)alloc((size_t)EA_ * 4);
    int* colC = (int*)alloc((size_t)ER_ * 4);
    int* cnt3 = (int*)alloc((size_t)3 * NN * 4);   // counts, then reused as cursors
    int* part  = (int*)alloc(3 * NCH * 4);
    int* choff = (int*)alloc(3 * NCH * 4);

    const int TPB = 256;
    const int NE3 = ER_ + EA_ + ER_;
    dim3 e3grid((NE3 + TPB - 1) / TPB);

    // ---- CSR build ----
    hipMemsetAsync(cnt3, 0, (size_t)3 * NN * 4, stream);
    count3<<<e3grid, TPB, 0, stream>>>(dst_rev, dst_ab, src_rev, cnt3);
    scan_part<<<3 * NCH, TPB, 0, stream>>>(cnt3, part);
    scan_off<<<1, 64, 0, stream>>>(part, choff, ptrA, ptrB, ptrC);
    scan_apply<<<3 * NCH, TPB, 0, stream>>>(cnt3, choff, ptrA, ptrB, ptrC);
    hipMemsetAsync(cnt3, 0, (size_t)3 * NN * 4, stream);
    fill3<<<e3grid, TPB, 0, stream>>>(dst_rev, src_rev, dst_ab, src_ab,
                                      ptrA, ptrB, ptrC, cnt3, colA, colB, colC);

    // ---- fused prep (cvt x2 + wprep x10) ----
    PrepArgs PA;
    PA.xsrc[0] = x_user; PA.xdst[0] = xu;
    PA.xsrc[1] = x_item; PA.xdst[1] = xi;
    const float* W0s[10] = {Wl1_rev, Wl1_ab, Wl1_rrev, Wr1_rev, Wr1_rrev,
                            Wl2_rev, Wl2_ab, Wl2_rrev, Wr2_rev, Wr2_rrev};
    const float* W1s[10] = {nullptr, nullptr, nullptr, Wr1_ab, nullptr,
                            nullptr, nullptr, nullptr, Wr2_ab, nullptr};
    ushort* Ts[10] = {wt_l1rev, wt_l1ab, wt_l1rrev, wt_r1c, wt_r1rrev,
                      wt_l2rev, wt_l2ab, wt_l2rrev, wt_r2c, wt_r2rrev};
    for (int i = 0; i < 10; i++) { PA.W0[i] = W0s[i]; PA.W1[i] = W1s[i]; PA.T[i] = Ts[i]; }
    const long CVB = (long)MPAD * 128 / 8 / 256;          // 6256
    const long WPB = (5 * 32768 + 5 * 65536 + 255) / 256; // 1920
    prep_all<<<(int)(2 * CVB + WPB), TPB, 0, stream>>>(PA);

    dim3 ggrid(MPAD / 128, 2, 2);

    auto mkGP = [&](const ushort* a0, const ushort* w0, int K0,
                    const ushort* a1, const ushort* w1, int K1,
                    const ushort* a2, const ushort* w2, int K2) {
        GP P;
        P.A0 = a0; P.W0 = w0;
        P.A1 = a1 ? a1 : a0; P.W1 = w1 ? w1 : w0;
        P.A2 = a2 ? a2 : a0; P.W2 = w2 ? w2 : w0;
        P.ksh0 = (K0 == 256) ? 8 : 7;
        P.ksh1 = (K1 == 256) ? 8 : 7;
        P.ksh2 = (K2 == 256) ? 8 : 7;
        P.c1 = K0 >> 6; P.c2 = P.c1 + (K1 >> 6); P.S = P.c2 + (K2 >> 6);
        return P;
    };

    // ---- layer 1 ----
    agg3_128<<<3 * (MPAD * 16 / 256), TPB, 0, stream>>>(xu, xi, ptrA, colA, ptrB, colB,
                                                        ptrC, colC, slabA, slabB, slabC);
    {
        GP P0 = mkGP(slabA, wt_l1rev, 128, slabB, wt_l1ab, 128, xi, wt_r1c, 128);
        GP P1 = mkGP(slabC, wt_l1rrev, 128, xu, wt_r1rrev, 128, nullptr, nullptr, 0);
        gemm2x<<<ggrid, TPB, 0, stream>>>(P0, b1_rev, b1_ab, nullptr, hI, F_RELU,
                                          P1, b1_rrev, nullptr, nullptr, hU, F_RELU);
    }

    // ---- layer 2 ----
    agg3_256<<<3 * (MPAD * 32 / 256), TPB, 0, stream>>>(hU, hI, ptrA, colA, ptrB, colB,
                                                        ptrC, colC, s2A, s2B, s2C);
    {
        GP P0 = mkGP(s2A, wt_l2rev, 256, s2B, wt_l2ab, 256, hI, wt_r2c, 256);
        GP P1 = mkGP(s2C, wt_l2rrev, 256, hU, wt_r2rrev, 256, nullptr, nullptr, 0);
        gemm2x<<<ggrid, TPB, 0, stream>>>(P0, b2_rev, b2_ab, o_item, nullptr, 0,
                                          P1, b2_rrev, nullptr, o_user, nullptr, 0);
    }
}